// Round 2
// baseline (732.896 us; speedup 1.0000x reference)
//
#include <hip/hip_runtime.h>
#include <hip/hip_bf16.h>

#define T_SEQ 1024
#define D_MOD 512
#define NHEAD 8
#define HDIM  64
#define R_DIM 512
#define BATCH 2

// runtime-dtype load/store: bf==1 -> bf16, bf==0 -> fp32.
// Branch is wave-uniform (flag same for all lanes); exec-masked lowering means
// the not-taken side issues no loads, so no speculative OOB access.
__device__ __forceinline__ float ldin(const void* p, size_t i, int bf) {
    if (bf) return __bfloat162float(((const __hip_bfloat16*)p)[i]);
    return ((const float*)p)[i];
}
__device__ __forceinline__ void stout(void* p, size_t i, int bf, float v) {
    if (bf) ((__hip_bfloat16*)p)[i] = __float2bfloat16(v);
    else    ((float*)p)[i] = v;
}

__device__ __forceinline__ float gelu_f(float x) {
    return 0.5f * x * (1.f + tanhf(0.7978845608028654f * (x + 0.044715f * x * x * x)));
}

// Detect input dtype from bit patterns of x. fp32 N(0,1) data: low 16 bits of
// mantissa are ~uniform -> ~0.4% of halves look like bf16 inf/nan (exp=0xFF).
// bf16 data of this scale: zero such patterns. flag=1 -> bf16.
__global__ __launch_bounds__(256) void detect_k(const void* __restrict__ x,
                                                int* __restrict__ flag)
{
    __shared__ int cnt;
    if (threadIdx.x == 0) cnt = 0;
    __syncthreads();
    const unsigned short* h = (const unsigned short*)x;
    int c = 0;
    for (int i = threadIdx.x; i < 8192; i += 256) {
        unsigned short v = h[i];
        if ((v & 0x7F80u) == 0x7F80u) c++;
    }
    atomicAdd(&cnt, c);
    __syncthreads();
    if (threadIdx.x == 0) *flag = (cnt == 0) ? 1 : 0;
}

// C = act(A @ B (+ bias)); A: MxK row-major; TRB: C = A @ Bw^T (Bw is [N][K])
// ADYN: A is an external input (dtype per flag); else A is fp32 workspace.
// ODYN: C is the external output (dtype per flag); else fp32 workspace.
template<int ACT, bool TRB, bool ADYN, bool ODYN>
__global__ __launch_bounds__(256) void gemm_k(const void* __restrict__ A,
                                              const void* __restrict__ Bw,
                                              const void* __restrict__ bias,
                                              void* __restrict__ C,
                                              int M, int N, int Kd,
                                              const int* __restrict__ flagp)
{
    const int bf = *flagp;
    __shared__ float As[16][72];
    __shared__ float Bs[16][72];
    const int tid = threadIdx.x;
    const int tx = tid & 15, ty = tid >> 4;
    const int m0 = blockIdx.y * 64, n0 = blockIdx.x * 64;
    float acc[4][4] = {};
    for (int k0 = 0; k0 < Kd; k0 += 16) {
        {
            const int mo = tid >> 2;
            const int ko = (tid & 3) * 4;
            const int m = m0 + mo;
            #pragma unroll
            for (int i = 0; i < 4; ++i) {
                const int k = k0 + ko + i;
                float av = 0.f;
                if (m < M && k < Kd)
                    av = ADYN ? ldin(A, (size_t)m * Kd + k, bf)
                              : ((const float*)A)[(size_t)m * Kd + k];
                As[ko + i][mo] = av;
            }
        }
        if (!TRB) {
            const int ko = tid >> 4;
            const int no = (tid & 15) * 4;
            const int k = k0 + ko;
            #pragma unroll
            for (int j = 0; j < 4; ++j) {
                const int n = n0 + no + j;
                Bs[ko][no + j] = (k < Kd && n < N) ? ldin(Bw, (size_t)k * N + n, bf) : 0.f;
            }
        } else {
            const int no = tid >> 2;
            const int ko = (tid & 3) * 4;
            const int n = n0 + no;
            #pragma unroll
            for (int i = 0; i < 4; ++i) {
                const int k = k0 + ko + i;
                Bs[ko + i][no] = (n < N && k < Kd) ? ldin(Bw, (size_t)n * Kd + k, bf) : 0.f;
            }
        }
        __syncthreads();
        #pragma unroll
        for (int kk = 0; kk < 16; ++kk) {
            float a[4], b[4];
            #pragma unroll
            for (int i = 0; i < 4; ++i) a[i] = As[kk][ty * 4 + i];
            #pragma unroll
            for (int j = 0; j < 4; ++j) b[j] = Bs[kk][tx * 4 + j];
            #pragma unroll
            for (int i = 0; i < 4; ++i)
                #pragma unroll
                for (int j = 0; j < 4; ++j)
                    acc[i][j] += a[i] * b[j];
        }
        __syncthreads();
    }
    #pragma unroll
    for (int i = 0; i < 4; ++i) {
        const int m = m0 + ty * 4 + i;
        if (m >= M) continue;
        #pragma unroll
        for (int j = 0; j < 4; ++j) {
            const int n = n0 + tx * 4 + j;
            if (n >= N) continue;
            float v = acc[i][j];
            if (bias) v += ldin(bias, (size_t)n, bf);
            if (ACT == 1) v = gelu_f(v);
            if (ACT == 2) v = 1.f / (1.f + expf(-v));
            if (ODYN) stout(C, (size_t)m * N + n, bf, v);
            else      ((float*)C)[(size_t)m * N + n] = v;
        }
    }
}

// w[b,t,r] = 2 * sum_{lag even, lag<=t} v[lag,r] * u[b,t-lag,r]   (all fp32 ws)
__global__ __launch_bounds__(256) void conv_k(const float* __restrict__ u,
                                              const float* __restrict__ v,
                                              float* __restrict__ w)
{
    const int r = blockIdx.x * 256 + threadIdx.x;
    const int t = blockIdx.y;
    const int b = blockIdx.z;
    const float* ub = u + (b * T_SEQ + t) * R_DIM + r;
    float acc = 0.f;
    for (int lag = 0; lag <= t; lag += 2)
        acc += v[lag * R_DIM + r] * ub[-lag * R_DIM];
    w[(b * T_SEQ + t) * R_DIM + r] = 2.f * acc;
}

// in-place layernorm over last dim (512); gamma/beta external dtype per flag
__global__ __launch_bounds__(256) void ln_k(float* __restrict__ w,
                                            const void* __restrict__ g,
                                            const void* __restrict__ b,
                                            const int* __restrict__ flagp)
{
    const int bf = *flagp;
    const int row = blockIdx.y * T_SEQ + blockIdx.x;
    float* p = w + (size_t)row * R_DIM;
    const int tid = threadIdx.x;
    const float x0 = p[tid], x1 = p[tid + 256];
    __shared__ float red[4];
    float s = x0 + x1;
    #pragma unroll
    for (int off = 32; off > 0; off >>= 1) s += __shfl_down(s, off, 64);
    if ((tid & 63) == 0) red[tid >> 6] = s;
    __syncthreads();
    const float mu = (red[0] + red[1] + red[2] + red[3]) * (1.f / 512.f);
    __syncthreads();
    const float d0 = x0 - mu, d1 = x1 - mu;
    float vs = d0 * d0 + d1 * d1;
    #pragma unroll
    for (int off = 32; off > 0; off >>= 1) vs += __shfl_down(vs, off, 64);
    if ((tid & 63) == 0) red[tid >> 6] = vs;
    __syncthreads();
    const float var = (red[0] + red[1] + red[2] + red[3]) * (1.f / 512.f);
    const float rs = rsqrtf(var + 1e-5f);
    p[tid]       = d0 * rs * ldin(g, tid, bf)       + ldin(b, tid, bf);
    p[tid + 256] = d1 * rs * ldin(g, tid + 256, bf) + ldin(b, tid + 256, bf);
}

// Y = causal_mask(Q @ V^T) @ K per (b,h); Q/K/V/Y fp32, layout (b,t,h*64+p)
__global__ __launch_bounds__(256) void attn_k(const float* __restrict__ Qb,
                                              const float* __restrict__ Kb,
                                              const float* __restrict__ Vb,
                                              float* __restrict__ Yb)
{
    __shared__ float Qs[64][72];   // [p][tt]
    __shared__ float VK[64][72];   // V: [p][ss]; later K: [ss][n]
    __shared__ float Ss[64][65];   // [tt][ss]
    const int tid = threadIdx.x;
    const int tx = tid & 15, ty = tid >> 4;
    const int t0 = blockIdx.x * 64;
    const int h = blockIdx.y, b = blockIdx.z;
    const size_t base = ((size_t)b * T_SEQ) * D_MOD + h * HDIM;

    #pragma unroll
    for (int it = 0; it < 4; ++it) {
        const int tt = (tid >> 4) + it * 16;
        const int p0 = (tid & 15) * 4;
        const float4 q = *(const float4*)(Qb + base + (size_t)(t0 + tt) * D_MOD + p0);
        Qs[p0 + 0][tt] = q.x; Qs[p0 + 1][tt] = q.y;
        Qs[p0 + 2][tt] = q.z; Qs[p0 + 3][tt] = q.w;
    }
    float accY[4][4] = {};
    for (int s0 = 0; s0 <= t0; s0 += 64) {
        __syncthreads();
        #pragma unroll
        for (int it = 0; it < 4; ++it) {
            const int ss = (tid >> 4) + it * 16;
            const int p0 = (tid & 15) * 4;
            const float4 vv = *(const float4*)(Vb + base + (size_t)(s0 + ss) * D_MOD + p0);
            VK[p0 + 0][ss] = vv.x; VK[p0 + 1][ss] = vv.y;
            VK[p0 + 2][ss] = vv.z; VK[p0 + 3][ss] = vv.w;
        }
        __syncthreads();
        float acc[4][4] = {};
        #pragma unroll 8
        for (int p = 0; p < 64; ++p) {
            const float4 a4 = *(const float4*)&Qs[p][ty * 4];
            const float4 b4 = *(const float4*)&VK[p][tx * 4];
            const float a[4] = {a4.x, a4.y, a4.z, a4.w};
            const float bb[4] = {b4.x, b4.y, b4.z, b4.w};
            #pragma unroll
            for (int i = 0; i < 4; ++i)
                #pragma unroll
                for (int j = 0; j < 4; ++j)
                    acc[i][j] += a[i] * bb[j];
        }
        const bool diag = (s0 == t0);
        #pragma unroll
        for (int i = 0; i < 4; ++i)
            #pragma unroll
            for (int j = 0; j < 4; ++j) {
                float vS = acc[i][j];
                if (diag && (tx * 4 + j > ty * 4 + i)) vS = 0.f;
                Ss[ty * 4 + i][tx * 4 + j] = vS;
            }
        __syncthreads();
        #pragma unroll
        for (int it = 0; it < 4; ++it) {
            const int ss = (tid >> 4) + it * 16;
            const int n0 = (tid & 15) * 4;
            *(float4*)&VK[ss][n0] = *(const float4*)(Kb + base + (size_t)(s0 + ss) * D_MOD + n0);
        }
        __syncthreads();
        #pragma unroll 8
        for (int ss = 0; ss < 64; ++ss) {
            float a[4];
            #pragma unroll
            for (int i = 0; i < 4; ++i) a[i] = Ss[ty * 4 + i][ss];
            const float4 b4 = *(const float4*)&VK[ss][tx * 4];
            const float bb[4] = {b4.x, b4.y, b4.z, b4.w};
            #pragma unroll
            for (int i = 0; i < 4; ++i)
                #pragma unroll
                for (int j = 0; j < 4; ++j)
                    accY[i][j] += a[i] * bb[j];
        }
    }
    #pragma unroll
    for (int i = 0; i < 4; ++i)
        #pragma unroll
        for (int j = 0; j < 4; ++j)
            Yb[base + (size_t)(t0 + ty * 4 + i) * D_MOD + tx * 4 + j] = accY[i][j];
}

// comb = g*y + (1-g)*xt, in place into g   (all fp32 ws)
__global__ __launch_bounds__(256) void comb_k(float* __restrict__ g,
                                              const float* __restrict__ y,
                                              const float* __restrict__ xt)
{
    const int i = blockIdx.x * 256 + threadIdx.x;
    const float gg = g[i];
    g[i] = gg * y[i] + (1.f - gg) * xt[i];
}

extern "C" void kernel_launch(void* const* d_in, const int* in_sizes, int n_in,
                              void* d_out, int out_size, void* d_ws, size_t ws_size,
                              hipStream_t stream)
{
    const void* x   = d_in[0];
    const void* stf = d_in[1];
    const void* Mi  = d_in[2];
    const void* Mf  = d_in[3];
    const void* Wq  = d_in[4];  const void* bq = d_in[5];
    const void* Wk  = d_in[6];  const void* bk = d_in[7];
    const void* Wv  = d_in[8];  const void* bv = d_in[9];
    const void* Wg  = d_in[10]; const void* bg = d_in[11];
    const void* Wo  = d_in[12]; const void* bo = d_in[13];
    const void* lnw = d_in[14]; const void* lnb = d_in[15];

    int*   flag = (int*)d_ws;
    float* base = (float*)d_ws + 64;          // 256B offset, keeps 16B alignment
    float* f_u   = base;                      // u_proj -> Q -> (free)
    float* f_phi = base + 1048576;            // phi(0.5M) -> Y(1M)
    float* f_w   = base + 2 * 1048576;        // conv out -> x_tilde
    float* f_K   = base + 3 * 1048576;        // K -> gate -> comb
    float* f_V   = base + 4 * 1048576;        // V
    // total ws use: 256B + 20MB

    const int M = BATCH * T_SEQ;              // 2048
    dim3 blk(256);
    dim3 g_gemm(512 / 64, M / 64);
    dim3 g_phi(512 / 64, T_SEQ / 64);

    detect_k<<<1, blk, 0, stream>>>(x, flag);

    gemm_k<0, false, true, false><<<g_gemm, blk, 0, stream>>>(x, Mi, nullptr, f_u, M, 512, 512, flag);
    gemm_k<0, false, true, false><<<g_phi, blk, 0, stream>>>(stf, Mf, nullptr, f_phi, T_SEQ, 512, 24, flag);
    conv_k<<<dim3(2, T_SEQ, BATCH), blk, 0, stream>>>(f_u, f_phi, f_w);
    ln_k<<<dim3(T_SEQ, BATCH), blk, 0, stream>>>(f_w, lnw, lnb, flag);

    gemm_k<1, true, true, false><<<g_gemm, blk, 0, stream>>>(x, Wq, bq, f_u, M, 512, 512, flag);
    gemm_k<1, true, true, false><<<g_gemm, blk, 0, stream>>>(x, Wk, bk, f_K, M, 512, 512, flag);
    gemm_k<1, true, true, false><<<g_gemm, blk, 0, stream>>>(x, Wv, bv, f_V, M, 512, 512, flag);

    attn_k<<<dim3(T_SEQ / 64, NHEAD, BATCH), blk, 0, stream>>>(f_u, f_K, f_V, f_phi);

    gemm_k<2, true, true, false><<<g_gemm, blk, 0, stream>>>(x, Wg, bg, f_K, M, 512, 512, flag);
    comb_k<<<dim3((BATCH * T_SEQ * D_MOD) / 256), blk, 0, stream>>>(f_K, f_phi, f_w);

    gemm_k<0, true, false, true><<<g_gemm, blk, 0, stream>>>(f_K, Wo, bo, d_out, M, 512, 512, flag);
}

// Round 3
// 376.538 us; speedup vs baseline: 1.9464x; 1.9464x over previous
//
#include <hip/hip_runtime.h>
#include <hip/hip_bf16.h>

#define T_SEQ 1024
#define D_MOD 512
#define NHEAD 8
#define HDIM  64
#define R_DIM 512
#define BATCH 2

typedef __attribute__((ext_vector_type(8))) __bf16 bf16x8;
typedef __attribute__((ext_vector_type(4))) float f32x4;

// runtime-dtype load/store: bf==1 -> bf16, bf==0 -> fp32 (wave-uniform branch)
__device__ __forceinline__ float ldin(const void* p, size_t i, int bf) {
    if (bf) return __bfloat162float(((const __hip_bfloat16*)p)[i]);
    return ((const float*)p)[i];
}
__device__ __forceinline__ void stout(void* p, size_t i, int bf, float v) {
    if (bf) ((__hip_bfloat16*)p)[i] = __float2bfloat16(v);
    else    ((float*)p)[i] = v;
}

__device__ __forceinline__ float gelu_f(float x) {
    return 0.5f * x * (1.f + tanhf(0.7978845608028654f * (x + 0.044715f * x * x * x)));
}

// dtype sniffing: fp32 N(0,1) data has ~0.4% of 16-bit halves matching bf16
// inf/nan exponent; true bf16 data has none. flag=1 -> bf16.
__global__ __launch_bounds__(256) void detect_k(const void* __restrict__ x,
                                                int* __restrict__ flag)
{
    __shared__ int cnt;
    if (threadIdx.x == 0) cnt = 0;
    __syncthreads();
    const unsigned short* h = (const unsigned short*)x;
    int c = 0;
    for (int i = threadIdx.x; i < 8192; i += 256) {
        unsigned short v = h[i];
        if ((v & 0x7F80u) == 0x7F80u) c++;
    }
    atomicAdd(&cnt, c);
    __syncthreads();
    if (threadIdx.x == 0) *flag = (cnt == 0) ? 1 : 0;
}

// ---------------- MFMA bf16 GEMM: C = act(A @ B (+bias)) ----------------
// M%64==0, N%64==0, Kd%32==0. TRB: Bw is [N][K] row-major (C = A @ Bw^T),
// else Bw is [K][N]. ADYN: A external (dtype per flag) else fp32 ws.
// ODYN: C external (dtype per flag) else fp32 ws.
template<int ACT, bool TRB, bool ADYN, bool ODYN>
__global__ __launch_bounds__(256) void gemm_mfma(const void* __restrict__ A,
                                                 const void* __restrict__ Bw,
                                                 const void* __restrict__ bias,
                                                 void* __restrict__ C,
                                                 int M, int N, int Kd,
                                                 const int* __restrict__ flagp)
{
    const int bf = *flagp;
    __shared__ __align__(16) __bf16 As[64][40];   // [m][k], k-step 32, pad->40
    __shared__ __align__(16) __bf16 Bs[64][40];   // [n][k]
    const int tid = threadIdx.x;
    const int wave = tid >> 6, lane = tid & 63;
    const int lm = lane & 15, kq = lane >> 4;
    const int m0 = blockIdx.y * 64, n0 = blockIdx.x * 64;

    f32x4 acc[4] = {{0.f,0.f,0.f,0.f},{0.f,0.f,0.f,0.f},
                    {0.f,0.f,0.f,0.f},{0.f,0.f,0.f,0.f}};

    for (int k0 = 0; k0 < Kd; k0 += 32) {
        if (k0) __syncthreads();
        // stage A tile 64x32
        {
            const int mo = tid >> 2;
            const int ko = (tid & 3) * 8;
            const size_t off = (size_t)(m0 + mo) * Kd + k0 + ko;
            if (ADYN && bf) {
                *(bf16x8*)&As[mo][ko] = *(const bf16x8*)((const __bf16*)A + off);
            } else {
                const float* Af = (const float*)A + off;
                const float4 f0 = *(const float4*)Af;
                const float4 f1 = *(const float4*)(Af + 4);
                bf16x8 t;
                t[0]=(__bf16)f0.x; t[1]=(__bf16)f0.y; t[2]=(__bf16)f0.z; t[3]=(__bf16)f0.w;
                t[4]=(__bf16)f1.x; t[5]=(__bf16)f1.y; t[6]=(__bf16)f1.z; t[7]=(__bf16)f1.w;
                *(bf16x8*)&As[mo][ko] = t;
            }
        }
        // stage B tile -> Bs[n][k]
        if (TRB) {
            const int no = tid >> 2;
            const int ko = (tid & 3) * 8;
            const size_t off = (size_t)(n0 + no) * Kd + k0 + ko;
            if (bf) {
                *(bf16x8*)&Bs[no][ko] = *(const bf16x8*)((const __bf16*)Bw + off);
            } else {
                const float* Bf = (const float*)Bw + off;
                const float4 f0 = *(const float4*)Bf;
                const float4 f1 = *(const float4*)(Bf + 4);
                bf16x8 t;
                t[0]=(__bf16)f0.x; t[1]=(__bf16)f0.y; t[2]=(__bf16)f0.z; t[3]=(__bf16)f0.w;
                t[4]=(__bf16)f1.x; t[5]=(__bf16)f1.y; t[6]=(__bf16)f1.z; t[7]=(__bf16)f1.w;
                *(bf16x8*)&Bs[no][ko] = t;
            }
        } else {
            const int kk = tid >> 3;            // 0..31
            const int nn = (tid & 7) * 8;
            const size_t off = (size_t)(k0 + kk) * N + n0 + nn;
            if (bf) {
                const bf16x8 t = *(const bf16x8*)((const __bf16*)Bw + off);
                #pragma unroll
                for (int j = 0; j < 8; ++j) Bs[nn + j][kk] = t[j];
            } else {
                const float* Bf = (const float*)Bw + off;
                #pragma unroll
                for (int j = 0; j < 8; ++j) Bs[nn + j][kk] = (__bf16)Bf[j];
            }
        }
        __syncthreads();
        const bf16x8 a = *(const bf16x8*)&As[wave * 16 + lm][kq * 8];
        #pragma unroll
        for (int nt = 0; nt < 4; ++nt) {
            const bf16x8 b = *(const bf16x8*)&Bs[nt * 16 + lm][kq * 8];
            acc[nt] = __builtin_amdgcn_mfma_f32_16x16x32_bf16(a, b, acc[nt], 0, 0, 0);
        }
    }
    // epilogue: D[m][n]: m = kq*4+reg, n = lm  (m89-verified mapping)
    #pragma unroll
    for (int nt = 0; nt < 4; ++nt) {
        const int n = n0 + nt * 16 + lm;
        #pragma unroll
        for (int r2 = 0; r2 < 4; ++r2) {
            const int m = m0 + wave * 16 + kq * 4 + r2;
            float v = acc[nt][r2];
            if (bias) v += ldin(bias, (size_t)n, bf);
            if (ACT == 1) v = gelu_f(v);
            if (ACT == 2) v = 1.f / (1.f + expf(-v));
            if (ODYN) stout(C, (size_t)m * N + n, bf, v);
            else      ((float*)C)[(size_t)m * N + n] = v;
        }
    }
}

// ---------------- small fp32 GEMM (phi projection, K=24) ----------------
template<int ACT, bool TRB, bool ADYN, bool ODYN>
__global__ __launch_bounds__(256) void gemm_k(const void* __restrict__ A,
                                              const void* __restrict__ Bw,
                                              const void* __restrict__ bias,
                                              void* __restrict__ C,
                                              int M, int N, int Kd,
                                              const int* __restrict__ flagp)
{
    const int bf = *flagp;
    __shared__ float As[16][72];
    __shared__ float Bs[16][72];
    const int tid = threadIdx.x;
    const int tx = tid & 15, ty = tid >> 4;
    const int m0 = blockIdx.y * 64, n0 = blockIdx.x * 64;
    float acc[4][4] = {};
    for (int k0 = 0; k0 < Kd; k0 += 16) {
        {
            const int mo = tid >> 2;
            const int ko = (tid & 3) * 4;
            const int m = m0 + mo;
            #pragma unroll
            for (int i = 0; i < 4; ++i) {
                const int k = k0 + ko + i;
                float av = 0.f;
                if (m < M && k < Kd)
                    av = ADYN ? ldin(A, (size_t)m * Kd + k, bf)
                              : ((const float*)A)[(size_t)m * Kd + k];
                As[ko + i][mo] = av;
            }
        }
        if (!TRB) {
            const int ko = tid >> 4;
            const int no = (tid & 15) * 4;
            const int k = k0 + ko;
            #pragma unroll
            for (int j = 0; j < 4; ++j) {
                const int n = n0 + no + j;
                Bs[ko][no + j] = (k < Kd && n < N) ? ldin(Bw, (size_t)k * N + n, bf) : 0.f;
            }
        } else {
            const int no = tid >> 2;
            const int ko = (tid & 3) * 4;
            const int n = n0 + no;
            #pragma unroll
            for (int i = 0; i < 4; ++i) {
                const int k = k0 + ko + i;
                Bs[ko + i][no] = (n < N && k < Kd) ? ldin(Bw, (size_t)n * Kd + k, bf) : 0.f;
            }
        }
        __syncthreads();
        #pragma unroll
        for (int kk = 0; kk < 16; ++kk) {
            float a[4], b[4];
            #pragma unroll
            for (int i = 0; i < 4; ++i) a[i] = As[kk][ty * 4 + i];
            #pragma unroll
            for (int j = 0; j < 4; ++j) b[j] = Bs[kk][tx * 4 + j];
            #pragma unroll
            for (int i = 0; i < 4; ++i)
                #pragma unroll
                for (int j = 0; j < 4; ++j)
                    acc[i][j] += a[i] * b[j];
        }
        __syncthreads();
    }
    #pragma unroll
    for (int i = 0; i < 4; ++i) {
        const int m = m0 + ty * 4 + i;
        if (m >= M) continue;
        #pragma unroll
        for (int j = 0; j < 4; ++j) {
            const int n = n0 + tx * 4 + j;
            if (n >= N) continue;
            float v = acc[i][j];
            if (bias) v += ldin(bias, (size_t)n, bf);
            if (ACT == 1) v = gelu_f(v);
            if (ACT == 2) v = 1.f / (1.f + expf(-v));
            if (ODYN) stout(C, (size_t)m * N + n, bf, v);
            else      ((float*)C)[(size_t)m * N + n] = v;
        }
    }
}

// -------- tiled even-lag causal conv: w[b,t,r] = 2*sum_{lag even<=t} v[lag,r]*u[b,t-lag,r]
// block: 64 t x 64 r; thread: 16 t x 1 r; lag-tiles of 64 staged in LDS.
__global__ __launch_bounds__(256) void conv_tile_k(const float* __restrict__ u,
                                                   const float* __restrict__ v,
                                                   float* __restrict__ w)
{
    __shared__ float vs[64][64];    // [lag - L0][r - r0]
    __shared__ float us[128][64];   // [s - W0][r - r0]
    const int tid = threadIdx.x;
    const int rl = tid & 63;
    const int tg = tid >> 6;              // 0..3 -> 16 t's each
    const int t0 = blockIdx.x * 64;
    const int r0 = blockIdx.y * 64;
    const int b  = blockIdx.z;
    const float* ub = u + (size_t)b * T_SEQ * R_DIM;

    float acc[16] = {};

    for (int L0 = 0; L0 <= t0; L0 += 64) {
        if (L0) __syncthreads();
        const int W0 = t0 - L0 - 63;
        // stage u window: 128 rows x 64 cols
        #pragma unroll
        for (int j = 0; j < 8; ++j) {
            const int n = j * 256 + tid;           // 0..2047
            const int row = n >> 4, c4 = (n & 15) * 4;
            int s = W0 + row;
            s = s < 0 ? 0 : (s > T_SEQ - 1 ? T_SEQ - 1 : s);
            *(float4*)&us[row][c4] = *(const float4*)&ub[(size_t)s * R_DIM + r0 + c4];
        }
        // stage v tile: 64 rows x 64 cols
        #pragma unroll
        for (int j = 0; j < 4; ++j) {
            const int n = j * 256 + tid;           // 0..1023
            const int row = n >> 4, c4 = (n & 15) * 4;
            *(float4*)&vs[row][c4] = *(const float4*)&v[(size_t)(L0 + row) * R_DIM + r0 + c4];
        }
        __syncthreads();

        if (L0 < t0) {
            // full tile: all 32 even lags apply to all 64 t's
            #pragma unroll
            for (int g = 0; g < 4; ++g) {
                const int wsmin = tg * 16 + 49 - 16 * g;
                float ur[30];
                #pragma unroll
                for (int j = 0; j < 30; ++j) ur[j] = us[wsmin + j][rl];
                float vr[8];
                #pragma unroll
                for (int e = 0; e < 8; ++e) vr[e] = vs[16 * g + 2 * e][rl];
                #pragma unroll
                for (int e = 0; e < 8; ++e)
                    #pragma unroll
                    for (int i = 0; i < 16; ++i)
                        acc[i] += vr[e] * ur[i - 2 * e + 14];
            }
        } else {
            // diagonal tile: lag = t0 + l needs l <= t - t0; s = t - lag in [0,63]
            for (int l = 0; l < 64; l += 2) {
                const float vv = vs[l][rl];
                #pragma unroll
                for (int i = 0; i < 16; ++i) {
                    const int srel = tg * 16 + i - l;
                    if (srel >= 0) acc[i] += vv * us[srel + 63][rl];
                }
            }
        }
    }
    #pragma unroll
    for (int i = 0; i < 16; ++i)
        w[((size_t)b * T_SEQ + t0 + tg * 16 + i) * R_DIM + r0 + rl] = 2.f * acc[i];
}

// in-place layernorm over last dim (512)
__global__ __launch_bounds__(256) void ln_k(float* __restrict__ w,
                                            const void* __restrict__ g,
                                            const void* __restrict__ b,
                                            const int* __restrict__ flagp)
{
    const int bf = *flagp;
    const int row = blockIdx.y * T_SEQ + blockIdx.x;
    float* p = w + (size_t)row * R_DIM;
    const int tid = threadIdx.x;
    const float x0 = p[tid], x1 = p[tid + 256];
    __shared__ float red[4];
    float s = x0 + x1;
    #pragma unroll
    for (int off = 32; off > 0; off >>= 1) s += __shfl_down(s, off, 64);
    if ((tid & 63) == 0) red[tid >> 6] = s;
    __syncthreads();
    const float mu = (red[0] + red[1] + red[2] + red[3]) * (1.f / 512.f);
    __syncthreads();
    const float d0 = x0 - mu, d1 = x1 - mu;
    float vs = d0 * d0 + d1 * d1;
    #pragma unroll
    for (int off = 32; off > 0; off >>= 1) vs += __shfl_down(vs, off, 64);
    if ((tid & 63) == 0) red[tid >> 6] = vs;
    __syncthreads();
    const float var = (red[0] + red[1] + red[2] + red[3]) * (1.f / 512.f);
    const float rs = rsqrtf(var + 1e-5f);
    p[tid]       = d0 * rs * ldin(g, tid, bf)       + ldin(b, tid, bf);
    p[tid + 256] = d1 * rs * ldin(g, tid + 256, bf) + ldin(b, tid + 256, bf);
}

// Y = causal_mask(Q @ V^T) @ K per (b,h); fp32, layout (b,t,h*64+p)
__global__ __launch_bounds__(256) void attn_k(const float* __restrict__ Qb,
                                              const float* __restrict__ Kb,
                                              const float* __restrict__ Vb,
                                              float* __restrict__ Yb)
{
    __shared__ float Qs[64][72];
    __shared__ float VK[64][72];
    __shared__ float Ss[64][65];
    const int tid = threadIdx.x;
    const int tx = tid & 15, ty = tid >> 4;
    const int t0 = blockIdx.x * 64;
    const int h = blockIdx.y, b = blockIdx.z;
    const size_t base = ((size_t)b * T_SEQ) * D_MOD + h * HDIM;

    #pragma unroll
    for (int it = 0; it < 4; ++it) {
        const int tt = (tid >> 4) + it * 16;
        const int p0 = (tid & 15) * 4;
        const float4 q = *(const float4*)(Qb + base + (size_t)(t0 + tt) * D_MOD + p0);
        Qs[p0 + 0][tt] = q.x; Qs[p0 + 1][tt] = q.y;
        Qs[p0 + 2][tt] = q.z; Qs[p0 + 3][tt] = q.w;
    }
    float accY[4][4] = {};
    for (int s0 = 0; s0 <= t0; s0 += 64) {
        __syncthreads();
        #pragma unroll
        for (int it = 0; it < 4; ++it) {
            const int ss = (tid >> 4) + it * 16;
            const int p0 = (tid & 15) * 4;
            const float4 vv = *(const float4*)(Vb + base + (size_t)(s0 + ss) * D_MOD + p0);
            VK[p0 + 0][ss] = vv.x; VK[p0 + 1][ss] = vv.y;
            VK[p0 + 2][ss] = vv.z; VK[p0 + 3][ss] = vv.w;
        }
        __syncthreads();
        float acc[4][4] = {};
        #pragma unroll 8
        for (int p = 0; p < 64; ++p) {
            const float4 a4 = *(const float4*)&Qs[p][ty * 4];
            const float4 b4 = *(const float4*)&VK[p][tx * 4];
            const float a[4] = {a4.x, a4.y, a4.z, a4.w};
            const float bb[4] = {b4.x, b4.y, b4.z, b4.w};
            #pragma unroll
            for (int i = 0; i < 4; ++i)
                #pragma unroll
                for (int j = 0; j < 4; ++j)
                    acc[i][j] += a[i] * bb[j];
        }
        const bool diag = (s0 == t0);
        #pragma unroll
        for (int i = 0; i < 4; ++i)
            #pragma unroll
            for (int j = 0; j < 4; ++j) {
                float vS = acc[i][j];
                if (diag && (tx * 4 + j > ty * 4 + i)) vS = 0.f;
                Ss[ty * 4 + i][tx * 4 + j] = vS;
            }
        __syncthreads();
        #pragma unroll
        for (int it = 0; it < 4; ++it) {
            const int ss = (tid >> 4) + it * 16;
            const int n0 = (tid & 15) * 4;
            *(float4*)&VK[ss][n0] = *(const float4*)(Kb + base + (size_t)(s0 + ss) * D_MOD + n0);
        }
        __syncthreads();
        #pragma unroll 8
        for (int ss = 0; ss < 64; ++ss) {
            float a[4];
            #pragma unroll
            for (int i = 0; i < 4; ++i) a[i] = Ss[ty * 4 + i][ss];
            const float4 b4 = *(const float4*)&VK[ss][tx * 4];
            const float bb[4] = {b4.x, b4.y, b4.z, b4.w};
            #pragma unroll
            for (int i = 0; i < 4; ++i)
                #pragma unroll
                for (int j = 0; j < 4; ++j)
                    accY[i][j] += a[i] * bb[j];
        }
    }
    #pragma unroll
    for (int i = 0; i < 4; ++i)
        #pragma unroll
        for (int j = 0; j < 4; ++j)
            Yb[base + (size_t)(t0 + ty * 4 + i) * D_MOD + tx * 4 + j] = accY[i][j];
}

// comb = g*y + (1-g)*xt, in place into g
__global__ __launch_bounds__(256) void comb_k(float* __restrict__ g,
                                              const float* __restrict__ y,
                                              const float* __restrict__ xt)
{
    const int i = blockIdx.x * 256 + threadIdx.x;
    const float gg = g[i];
    g[i] = gg * y[i] + (1.f - gg) * xt[i];
}

extern "C" void kernel_launch(void* const* d_in, const int* in_sizes, int n_in,
                              void* d_out, int out_size, void* d_ws, size_t ws_size,
                              hipStream_t stream)
{
    const void* x   = d_in[0];
    const void* stf = d_in[1];
    const void* Mi  = d_in[2];
    const void* Mf  = d_in[3];
    const void* Wq  = d_in[4];  const void* bq = d_in[5];
    const void* Wk  = d_in[6];  const void* bk = d_in[7];
    const void* Wv  = d_in[8];  const void* bv = d_in[9];
    const void* Wg  = d_in[10]; const void* bg = d_in[11];
    const void* Wo  = d_in[12]; const void* bo = d_in[13];
    const void* lnw = d_in[14]; const void* lnb = d_in[15];

    int*   flag = (int*)d_ws;
    float* base = (float*)d_ws + 64;
    float* f_u   = base;                      // u_proj -> Q -> (free)
    float* f_phi = base + 1048576;            // phi(0.5M) -> Y(1M)
    float* f_w   = base + 2 * 1048576;        // conv out -> x_tilde
    float* f_K   = base + 3 * 1048576;        // K -> gate -> comb
    float* f_V   = base + 4 * 1048576;        // V

    const int M = BATCH * T_SEQ;              // 2048
    dim3 blk(256);
    dim3 g_gemm(512 / 64, M / 64);
    dim3 g_phi(512 / 64, T_SEQ / 64);

    detect_k<<<1, blk, 0, stream>>>(x, flag);

    gemm_mfma<0, false, true, false><<<g_gemm, blk, 0, stream>>>(x, Mi, nullptr, f_u, M, 512, 512, flag);
    gemm_k<0, false, true, false><<<g_phi, blk, 0, stream>>>(stf, Mf, nullptr, f_phi, T_SEQ, 512, 24, flag);
    conv_tile_k<<<dim3(T_SEQ / 64, R_DIM / 64, BATCH), blk, 0, stream>>>(f_u, f_phi, f_w);
    ln_k<<<dim3(T_SEQ, BATCH), blk, 0, stream>>>(f_w, lnw, lnb, flag);

    gemm_mfma<1, true, true, false><<<g_gemm, blk, 0, stream>>>(x, Wq, bq, f_u, M, 512, 512, flag);
    gemm_mfma<1, true, true, false><<<g_gemm, blk, 0, stream>>>(x, Wk, bk, f_K, M, 512, 512, flag);
    gemm_mfma<1, true, true, false><<<g_gemm, blk, 0, stream>>>(x, Wv, bv, f_V, M, 512, 512, flag);

    attn_k<<<dim3(T_SEQ / 64, NHEAD, BATCH), blk, 0, stream>>>(f_u, f_K, f_V, f_phi);

    gemm_mfma<2, true, true, false><<<g_gemm, blk, 0, stream>>>(x, Wg, bg, f_K, M, 512, 512, flag);
    comb_k<<<dim3((BATCH * T_SEQ * D_MOD) / 256), blk, 0, stream>>>(f_K, f_phi, f_w);

    gemm_mfma<0, true, false, true><<<g_gemm, blk, 0, stream>>>(f_K, Wo, bo, d_out, M, 512, 512, flag);
}

// Round 4
// 225.983 us; speedup vs baseline: 3.2431x; 1.6662x over previous
//
#include <hip/hip_runtime.h>
#include <hip/hip_bf16.h>

#define T_SEQ 1024
#define D_MOD 512
#define NHEAD 8
#define HDIM  64
#define R_DIM 512
#define BATCH 2

typedef __attribute__((ext_vector_type(8))) __bf16 bf16x8;
typedef __attribute__((ext_vector_type(4))) float f32x4;

// runtime-dtype load/store: bf==1 -> bf16, bf==0 -> fp32 (wave-uniform branch)
__device__ __forceinline__ float ldin(const void* p, size_t i, int bf) {
    if (bf) return __bfloat162float(((const __hip_bfloat16*)p)[i]);
    return ((const float*)p)[i];
}
__device__ __forceinline__ void stout(void* p, size_t i, int bf, float v) {
    if (bf) ((__hip_bfloat16*)p)[i] = __float2bfloat16(v);
    else    ((float*)p)[i] = v;
}

__device__ __forceinline__ float gelu_f(float x) {
    return 0.5f * x * (1.f + tanhf(0.7978845608028654f * (x + 0.044715f * x * x * x)));
}

// dtype sniffing: fp32 N(0,1) data has ~0.4% of 16-bit halves matching bf16
// inf/nan exponent; true bf16 data has none. flag=1 -> bf16.
__global__ __launch_bounds__(256) void detect_k(const void* __restrict__ x,
                                                int* __restrict__ flag)
{
    __shared__ int cnt;
    if (threadIdx.x == 0) cnt = 0;
    __syncthreads();
    const unsigned short* h = (const unsigned short*)x;
    int c = 0;
    for (int i = threadIdx.x; i < 8192; i += 256) {
        unsigned short v = h[i];
        if ((v & 0x7F80u) == 0x7F80u) c++;
    }
    atomicAdd(&cnt, c);
    __syncthreads();
    if (threadIdx.x == 0) *flag = (cnt == 0) ? 1 : 0;
}

// ---------------- fused projection GEMMs, one dispatch ----------------
// job 0: u   = x @ Mi                  -> fp32 fu    (M=2048, K=512, B=[K][N])
// job 1: Q   = gelu(x @ Wq^T + bq)     -> bf16 fQ    (B=[N][K])
// job 2: K   = gelu(x @ Wk^T + bk)     -> bf16 fK
// job 3: V   = gelu(x @ Wv^T + bv)     -> bf16 fV
// job 4: G   = sigmoid(x @ Wg^T + bg)  -> bf16 fG
// job 5: phi = stf @ Mf                -> fp32 fphi  (M=1024, K=24 pad 32, B=[K][N])
__global__ __launch_bounds__(256) void mega_gemm(
    const void* __restrict__ x, const void* __restrict__ Mi,
    const void* __restrict__ stf, const void* __restrict__ Mf,
    const void* __restrict__ Wq, const void* __restrict__ bq,
    const void* __restrict__ Wk, const void* __restrict__ bk,
    const void* __restrict__ Wv, const void* __restrict__ bv,
    const void* __restrict__ Wg, const void* __restrict__ bg,
    float* __restrict__ fu, float* __restrict__ fphi,
    __bf16* __restrict__ fQ, __bf16* __restrict__ fK,
    __bf16* __restrict__ fV, __bf16* __restrict__ fG,
    const int* __restrict__ flagp)
{
    const int bf = *flagp;
    const int job = blockIdx.z;
    const void* A = x; const void* Bw; const void* bias = nullptr;
    int Kd = 512, act = 0; bool trb = true;
    float* of = nullptr; __bf16* ob = nullptr;
    switch (job) {
        case 0: Bw = Mi; trb = false; of = fu; break;
        case 1: Bw = Wq; bias = bq; act = 1; ob = fQ; break;
        case 2: Bw = Wk; bias = bk; act = 1; ob = fK; break;
        case 3: Bw = Wv; bias = bv; act = 1; ob = fV; break;
        case 4: Bw = Wg; bias = bg; act = 2; ob = fG; break;
        default: A = stf; Bw = Mf; trb = false; of = fphi; Kd = 32; break;
    }
    const int M = (job == 5) ? 1024 : 2048;
    const int m0 = blockIdx.y * 64;
    if (m0 >= M) return;
    const int n0 = blockIdx.x * 64;

    __shared__ __align__(16) __bf16 As[64][40];
    __shared__ __align__(16) __bf16 Bs[64][40];
    const int tid = threadIdx.x;
    const int wave = tid >> 6, lane = tid & 63;
    const int lm = lane & 15, kq = lane >> 4;

    f32x4 acc[4] = {{0.f,0.f,0.f,0.f},{0.f,0.f,0.f,0.f},
                    {0.f,0.f,0.f,0.f},{0.f,0.f,0.f,0.f}};

    for (int k0 = 0; k0 < Kd; k0 += 32) {
        if (k0) __syncthreads();
        // stage A tile 64x32
        {
            const int mo = tid >> 2;
            const int ko = (tid & 3) * 8;
            if (job == 5) {
                #pragma unroll
                for (int q = 0; q < 8; ++q) {
                    const int k = ko + q;
                    As[mo][k] = (k < 24) ? (__bf16)ldin(A, (size_t)(m0 + mo) * 24 + k, bf)
                                         : (__bf16)0.f;
                }
            } else {
                const size_t off = (size_t)(m0 + mo) * 512 + k0 + ko;
                if (bf) {
                    *(bf16x8*)&As[mo][ko] = *(const bf16x8*)((const __bf16*)A + off);
                } else {
                    const float* Af = (const float*)A + off;
                    const float4 f0 = *(const float4*)Af;
                    const float4 f1 = *(const float4*)(Af + 4);
                    bf16x8 t;
                    t[0]=(__bf16)f0.x; t[1]=(__bf16)f0.y; t[2]=(__bf16)f0.z; t[3]=(__bf16)f0.w;
                    t[4]=(__bf16)f1.x; t[5]=(__bf16)f1.y; t[6]=(__bf16)f1.z; t[7]=(__bf16)f1.w;
                    *(bf16x8*)&As[mo][ko] = t;
                }
            }
        }
        // stage B tile -> Bs[n][k]
        if (trb) {
            const int no = tid >> 2;
            const int ko = (tid & 3) * 8;
            const size_t off = (size_t)(n0 + no) * 512 + k0 + ko;
            if (bf) {
                *(bf16x8*)&Bs[no][ko] = *(const bf16x8*)((const __bf16*)Bw + off);
            } else {
                const float* Bf = (const float*)Bw + off;
                const float4 f0 = *(const float4*)Bf;
                const float4 f1 = *(const float4*)(Bf + 4);
                bf16x8 t;
                t[0]=(__bf16)f0.x; t[1]=(__bf16)f0.y; t[2]=(__bf16)f0.z; t[3]=(__bf16)f0.w;
                t[4]=(__bf16)f1.x; t[5]=(__bf16)f1.y; t[6]=(__bf16)f1.z; t[7]=(__bf16)f1.w;
                *(bf16x8*)&Bs[no][ko] = t;
            }
        } else {
            const int kk = tid >> 3;            // 0..31
            const int nn = (tid & 7) * 8;
            if (job == 5) {
                #pragma unroll
                for (int q = 0; q < 8; ++q)
                    Bs[nn + q][kk] = (kk < 24) ? (__bf16)ldin(Bw, (size_t)kk * 512 + n0 + nn + q, bf)
                                               : (__bf16)0.f;
            } else {
                const size_t off = (size_t)(k0 + kk) * 512 + n0 + nn;
                if (bf) {
                    const bf16x8 t = *(const bf16x8*)((const __bf16*)Bw + off);
                    #pragma unroll
                    for (int q = 0; q < 8; ++q) Bs[nn + q][kk] = t[q];
                } else {
                    const float* Bf = (const float*)Bw + off;
                    #pragma unroll
                    for (int q = 0; q < 8; ++q) Bs[nn + q][kk] = (__bf16)Bf[q];
                }
            }
        }
        __syncthreads();
        const bf16x8 a = *(const bf16x8*)&As[wave * 16 + lm][kq * 8];
        #pragma unroll
        for (int nt = 0; nt < 4; ++nt) {
            const bf16x8 b = *(const bf16x8*)&Bs[nt * 16 + lm][kq * 8];
            acc[nt] = __builtin_amdgcn_mfma_f32_16x16x32_bf16(a, b, acc[nt], 0, 0, 0);
        }
    }
    // epilogue: D[m][n]: m = wave*16 + kq*4 + r, n = nt*16 + lm
    #pragma unroll
    for (int nt = 0; nt < 4; ++nt) {
        const int n = n0 + nt * 16 + lm;
        #pragma unroll
        for (int r2 = 0; r2 < 4; ++r2) {
            const int m = m0 + wave * 16 + kq * 4 + r2;
            float v = acc[nt][r2];
            if (bias) v += ldin(bias, (size_t)n, bf);
            if (act == 1) v = gelu_f(v);
            if (act == 2) v = 1.f / (1.f + expf(-v));
            if (of) of[(size_t)m * 512 + n] = v;
            else    ob[(size_t)m * 512 + n] = (__bf16)v;
        }
    }
}

// -------- tiled even-lag causal conv: w[b,t,r] = 2*sum_{lag even<=t} v[lag,r]*u[b,t-lag,r]
__global__ __launch_bounds__(256) void conv_tile_k(const float* __restrict__ u,
                                                   const float* __restrict__ v,
                                                   float* __restrict__ w)
{
    __shared__ float vs[64][64];
    __shared__ float us[128][64];
    const int tid = threadIdx.x;
    const int rl = tid & 63;
    const int tg = tid >> 6;
    const int t0 = blockIdx.x * 64;
    const int r0 = blockIdx.y * 64;
    const int b  = blockIdx.z;
    const float* ub = u + (size_t)b * T_SEQ * R_DIM;

    float acc[16] = {};

    for (int L0 = 0; L0 <= t0; L0 += 64) {
        if (L0) __syncthreads();
        const int W0 = t0 - L0 - 63;
        #pragma unroll
        for (int j = 0; j < 8; ++j) {
            const int n = j * 256 + tid;
            const int row = n >> 4, c4 = (n & 15) * 4;
            int s = W0 + row;
            s = s < 0 ? 0 : (s > T_SEQ - 1 ? T_SEQ - 1 : s);
            *(float4*)&us[row][c4] = *(const float4*)&ub[(size_t)s * R_DIM + r0 + c4];
        }
        #pragma unroll
        for (int j = 0; j < 4; ++j) {
            const int n = j * 256 + tid;
            const int row = n >> 4, c4 = (n & 15) * 4;
            *(float4*)&vs[row][c4] = *(const float4*)&v[(size_t)(L0 + row) * R_DIM + r0 + c4];
        }
        __syncthreads();

        if (L0 < t0) {
            #pragma unroll
            for (int g = 0; g < 4; ++g) {
                const int wsmin = tg * 16 + 49 - 16 * g;
                float ur[30];
                #pragma unroll
                for (int j = 0; j < 30; ++j) ur[j] = us[wsmin + j][rl];
                float vr[8];
                #pragma unroll
                for (int e = 0; e < 8; ++e) vr[e] = vs[16 * g + 2 * e][rl];
                #pragma unroll
                for (int e = 0; e < 8; ++e)
                    #pragma unroll
                    for (int i = 0; i < 16; ++i)
                        acc[i] += vr[e] * ur[i - 2 * e + 14];
            }
        } else {
            for (int l = 0; l < 64; l += 2) {
                const float vv = vs[l][rl];
                #pragma unroll
                for (int i = 0; i < 16; ++i) {
                    const int srel = tg * 16 + i - l;
                    if (srel >= 0) acc[i] += vv * us[srel + 63][rl];
                }
            }
        }
    }
    #pragma unroll
    for (int i = 0; i < 16; ++i)
        w[((size_t)b * T_SEQ + t0 + tg * 16 + i) * R_DIM + r0 + rl] = 2.f * acc[i];
}

// in-place layernorm over last dim (512)
__global__ __launch_bounds__(256) void ln_k(float* __restrict__ w,
                                            const void* __restrict__ g,
                                            const void* __restrict__ b,
                                            const int* __restrict__ flagp)
{
    const int bf = *flagp;
    const int row = blockIdx.y * T_SEQ + blockIdx.x;
    float* p = w + (size_t)row * R_DIM;
    const int tid = threadIdx.x;
    const float x0 = p[tid], x1 = p[tid + 256];
    __shared__ float red[4];
    float s = x0 + x1;
    #pragma unroll
    for (int off = 32; off > 0; off >>= 1) s += __shfl_down(s, off, 64);
    if ((tid & 63) == 0) red[tid >> 6] = s;
    __syncthreads();
    const float mu = (red[0] + red[1] + red[2] + red[3]) * (1.f / 512.f);
    __syncthreads();
    const float d0 = x0 - mu, d1 = x1 - mu;
    float vs = d0 * d0 + d1 * d1;
    #pragma unroll
    for (int off = 32; off > 0; off >>= 1) vs += __shfl_down(vs, off, 64);
    if ((tid & 63) == 0) red[tid >> 6] = vs;
    __syncthreads();
    const float var = (red[0] + red[1] + red[2] + red[3]) * (1.f / 512.f);
    const float rs = rsqrtf(var + 1e-5f);
    p[tid]       = d0 * rs * ldin(g, tid, bf)       + ldin(b, tid, bf);
    p[tid + 256] = d1 * rs * ldin(g, tid + 256, bf) + ldin(b, tid + 256, bf);
}

// ---------------- MFMA attention: Y = tril(Q V^T) K per (b,h) ----------------
// Q/K/V bf16 in (b,t,h*64+p) layout; Y fp32 same layout.
__global__ __launch_bounds__(256) void attn_mfma(const __bf16* __restrict__ Q,
                                                 const __bf16* __restrict__ K,
                                                 const __bf16* __restrict__ V,
                                                 float* __restrict__ Y)
{
    __shared__ __align__(16) __bf16 Qs[64][72];   // [t][p]
    __shared__ __align__(16) __bf16 Vs[64][72];   // [s][p]
    __shared__ __align__(16) __bf16 Kt[64][72];   // [nh][s]
    __shared__ __align__(16) __bf16 Sa[64][72];   // [t][s]
    const int tid = threadIdx.x;
    const int wave = tid >> 6, lane = tid & 63;
    const int lm = lane & 15, kq = lane >> 4;
    const int ti = blockIdx.x;
    const int t0 = ti * 64;
    const int h = blockIdx.y, b = blockIdx.z;
    const size_t cbase = ((size_t)b * T_SEQ) * D_MOD + h * HDIM;

    #pragma unroll
    for (int it = 0; it < 2; ++it) {
        const int n = it * 256 + tid;
        const int row = n >> 3, p0 = (n & 7) * 8;
        *(bf16x8*)&Qs[row][p0] = *(const bf16x8*)&Q[cbase + (size_t)(t0 + row) * D_MOD + p0];
    }
    f32x4 accY[4] = {{0.f,0.f,0.f,0.f},{0.f,0.f,0.f,0.f},
                     {0.f,0.f,0.f,0.f},{0.f,0.f,0.f,0.f}};

    for (int j = 0; j <= ti; ++j) {
        __syncthreads();                        // staging below vs prior-iter reads
        const int s0 = j * 64;
        #pragma unroll
        for (int it = 0; it < 2; ++it) {
            const int n = it * 256 + tid;
            const int row = n >> 3, c0 = (n & 7) * 8;
            *(bf16x8*)&Vs[row][c0] = *(const bf16x8*)&V[cbase + (size_t)(s0 + row) * D_MOD + c0];
            const bf16x8 kv = *(const bf16x8*)&K[cbase + (size_t)(s0 + row) * D_MOD + c0];
            #pragma unroll
            for (int q = 0; q < 8; ++q) Kt[c0 + q][row] = kv[q];
        }
        __syncthreads();
        // matmul1: S[t][s] = sum_p Q[t][p] V[s][p]
        f32x4 sacc[4] = {{0.f,0.f,0.f,0.f},{0.f,0.f,0.f,0.f},
                         {0.f,0.f,0.f,0.f},{0.f,0.f,0.f,0.f}};
        #pragma unroll
        for (int ks = 0; ks < 2; ++ks) {
            const bf16x8 a = *(const bf16x8*)&Qs[wave * 16 + lm][ks * 32 + kq * 8];
            #pragma unroll
            for (int nt = 0; nt < 4; ++nt) {
                const bf16x8 bb = *(const bf16x8*)&Vs[nt * 16 + lm][ks * 32 + kq * 8];
                sacc[nt] = __builtin_amdgcn_mfma_f32_16x16x32_bf16(a, bb, sacc[nt], 0, 0, 0);
            }
        }
        // mask + stash S (bf16) in own wave's strip; no barrier needed:
        // wave w writes rows [w*16, w*16+16) and reads only those rows below.
        const bool diag = (j == ti);
        #pragma unroll
        for (int nt = 0; nt < 4; ++nt) {
            const int sl = nt * 16 + lm;
            #pragma unroll
            for (int r2 = 0; r2 < 4; ++r2) {
                const int tl = wave * 16 + kq * 4 + r2;
                float v = sacc[nt][r2];
                if (diag && sl > tl) v = 0.f;
                Sa[tl][sl] = (__bf16)v;
            }
        }
        // matmul2: Y[t][nh] += sum_s S[t][s] K[s][nh]
        #pragma unroll
        for (int ks = 0; ks < 2; ++ks) {
            const bf16x8 a = *(const bf16x8*)&Sa[wave * 16 + lm][ks * 32 + kq * 8];
            #pragma unroll
            for (int nt = 0; nt < 4; ++nt) {
                const bf16x8 bb = *(const bf16x8*)&Kt[nt * 16 + lm][ks * 32 + kq * 8];
                accY[nt] = __builtin_amdgcn_mfma_f32_16x16x32_bf16(a, bb, accY[nt], 0, 0, 0);
            }
        }
    }
    #pragma unroll
    for (int nt = 0; nt < 4; ++nt) {
        const int nh = nt * 16 + lm;
        #pragma unroll
        for (int r2 = 0; r2 < 4; ++r2) {
            const int tl = wave * 16 + kq * 4 + r2;
            Y[cbase + (size_t)(t0 + tl) * D_MOD + nh] = accY[nt][r2];
        }
    }
}

// ---------------- final GEMM with fused comb: out = (g*y+(1-g)*xt) @ Wo^T + bo
__global__ __launch_bounds__(256) void final_gemm(const __bf16* __restrict__ G,
                                                  const float* __restrict__ Yf,
                                                  const float* __restrict__ Xt,
                                                  const void* __restrict__ Wo,
                                                  const void* __restrict__ bo,
                                                  void* __restrict__ out,
                                                  const int* __restrict__ flagp)
{
    const int bf = *flagp;
    __shared__ __align__(16) __bf16 As[64][40];
    __shared__ __align__(16) __bf16 Bs[64][40];
    const int tid = threadIdx.x;
    const int wave = tid >> 6, lane = tid & 63;
    const int lm = lane & 15, kq = lane >> 4;
    const int m0 = blockIdx.y * 64, n0 = blockIdx.x * 64;

    f32x4 acc[4] = {{0.f,0.f,0.f,0.f},{0.f,0.f,0.f,0.f},
                    {0.f,0.f,0.f,0.f},{0.f,0.f,0.f,0.f}};

    for (int k0 = 0; k0 < 512; k0 += 32) {
        if (k0) __syncthreads();
        {
            const int mo = tid >> 2;
            const int ko = (tid & 3) * 8;
            const size_t off = (size_t)(m0 + mo) * 512 + k0 + ko;
            const bf16x8 g8 = *(const bf16x8*)(G + off);
            const float4 y0 = *(const float4*)(Yf + off);
            const float4 y1 = *(const float4*)(Yf + off + 4);
            const float4 x0 = *(const float4*)(Xt + off);
            const float4 x1 = *(const float4*)(Xt + off + 4);
            const float yv[8] = {y0.x,y0.y,y0.z,y0.w,y1.x,y1.y,y1.z,y1.w};
            const float xv[8] = {x0.x,x0.y,x0.z,x0.w,x1.x,x1.y,x1.z,x1.w};
            bf16x8 t;
            #pragma unroll
            for (int q = 0; q < 8; ++q) {
                const float gg = (float)g8[q];
                t[q] = (__bf16)(gg * yv[q] + (1.f - gg) * xv[q]);
            }
            *(bf16x8*)&As[mo][ko] = t;
        }
        {
            const int no = tid >> 2;
            const int ko = (tid & 3) * 8;
            const size_t off = (size_t)(n0 + no) * 512 + k0 + ko;
            if (bf) {
                *(bf16x8*)&Bs[no][ko] = *(const bf16x8*)((const __bf16*)Wo + off);
            } else {
                const float* Bf = (const float*)Wo + off;
                const float4 f0 = *(const float4*)Bf;
                const float4 f1 = *(const float4*)(Bf + 4);
                bf16x8 t;
                t[0]=(__bf16)f0.x; t[1]=(__bf16)f0.y; t[2]=(__bf16)f0.z; t[3]=(__bf16)f0.w;
                t[4]=(__bf16)f1.x; t[5]=(__bf16)f1.y; t[6]=(__bf16)f1.z; t[7]=(__bf16)f1.w;
                *(bf16x8*)&Bs[no][ko] = t;
            }
        }
        __syncthreads();
        const bf16x8 a = *(const bf16x8*)&As[wave * 16 + lm][kq * 8];
        #pragma unroll
        for (int nt = 0; nt < 4; ++nt) {
            const bf16x8 b = *(const bf16x8*)&Bs[nt * 16 + lm][kq * 8];
            acc[nt] = __builtin_amdgcn_mfma_f32_16x16x32_bf16(a, b, acc[nt], 0, 0, 0);
        }
    }
    #pragma unroll
    for (int nt = 0; nt < 4; ++nt) {
        const int n = n0 + nt * 16 + lm;
        #pragma unroll
        for (int r2 = 0; r2 < 4; ++r2) {
            const int m = m0 + wave * 16 + kq * 4 + r2;
            float v = acc[nt][r2] + ldin(bo, (size_t)n, bf);
            stout(out, (size_t)m * 512 + n, bf, v);
        }
    }
}

extern "C" void kernel_launch(void* const* d_in, const int* in_sizes, int n_in,
                              void* d_out, int out_size, void* d_ws, size_t ws_size,
                              hipStream_t stream)
{
    const void* x   = d_in[0];
    const void* stf = d_in[1];
    const void* Mi  = d_in[2];
    const void* Mf  = d_in[3];
    const void* Wq  = d_in[4];  const void* bq = d_in[5];
    const void* Wk  = d_in[6];  const void* bk = d_in[7];
    const void* Wv  = d_in[8];  const void* bv = d_in[9];
    const void* Wg  = d_in[10]; const void* bg = d_in[11];
    const void* Wo  = d_in[12]; const void* bo = d_in[13];
    const void* lnw = d_in[14]; const void* lnb = d_in[15];

    int*   flag  = (int*)d_ws;
    float* base  = (float*)d_ws + 64;
    float* f_u   = base;                        // u_proj -> (conv) -> Y
    float* f_phi = base + 1048576;              // phi (1024x512 fp32)
    float* f_w   = base + 1572864;              // conv out -> x_tilde
    __bf16* f_Q  = (__bf16*)(base + 2621440);   // bf16 2048x512 each
    __bf16* f_K  = f_Q + 1048576;
    __bf16* f_V  = f_K + 1048576;
    __bf16* f_G  = f_V + 1048576;
    // total ws: 256B + ~19MB

    dim3 blk(256);

    detect_k<<<1, blk, 0, stream>>>(x, flag);

    mega_gemm<<<dim3(8, 32, 6), blk, 0, stream>>>(
        x, Mi, stf, Mf, Wq, bq, Wk, bk, Wv, bv, Wg, bg,
        f_u, f_phi, f_Q, f_K, f_V, f_G, flag);

    conv_tile_k<<<dim3(T_SEQ / 64, R_DIM / 64, BATCH), blk, 0, stream>>>(f_u, f_phi, f_w);
    ln_k<<<dim3(T_SEQ, BATCH), blk, 0, stream>>>(f_w, lnw, lnb, flag);

    attn_mfma<<<dim3(T_SEQ / 64, NHEAD, BATCH), blk, 0, stream>>>(f_Q, f_K, f_V, f_u);

    final_gemm<<<dim3(8, 32), blk, 0, stream>>>(f_G, f_u, f_w, Wo, bo, d_out, flag);
}

// Round 5
// 212.403 us; speedup vs baseline: 3.4505x; 1.0639x over previous
//
#include <hip/hip_runtime.h>
#include <hip/hip_bf16.h>

#define T_SEQ 1024
#define D_MOD 512
#define NHEAD 8
#define HDIM  64
#define R_DIM 512
#define BATCH 2

typedef __attribute__((ext_vector_type(8))) __bf16 bf16x8;
typedef __attribute__((ext_vector_type(4))) float f32x4;

// runtime-dtype load/store: bf==1 -> bf16, bf==0 -> fp32 (wave-uniform branch)
__device__ __forceinline__ float ldin(const void* p, size_t i, int bf) {
    if (bf) return __bfloat162float(((const __hip_bfloat16*)p)[i]);
    return ((const float*)p)[i];
}
__device__ __forceinline__ void stout(void* p, size_t i, int bf, float v) {
    if (bf) ((__hip_bfloat16*)p)[i] = __float2bfloat16(v);
    else    ((float*)p)[i] = v;
}

__device__ __forceinline__ float gelu_f(float x) {
    return 0.5f * x * (1.f + tanhf(0.7978845608028654f * (x + 0.044715f * x * x * x)));
}

// dtype sniffing: fp32 N(0,1) data has ~0.4% of 16-bit halves matching bf16
// inf/nan exponent; true bf16 data has none. flag=1 -> bf16.
__global__ __launch_bounds__(256) void detect_k(const void* __restrict__ x,
                                                int* __restrict__ flag)
{
    __shared__ int cnt;
    if (threadIdx.x == 0) cnt = 0;
    __syncthreads();
    const unsigned short* h = (const unsigned short*)x;
    int c = 0;
    for (int i = threadIdx.x; i < 8192; i += 256) {
        unsigned short v = h[i];
        if ((v & 0x7F80u) == 0x7F80u) c++;
    }
    atomicAdd(&cnt, c);
    __syncthreads();
    if (threadIdx.x == 0) *flag = (cnt == 0) ? 1 : 0;
}

// ---------------- fused projection GEMMs, one dispatch ----------------
__global__ __launch_bounds__(256) void mega_gemm(
    const void* __restrict__ x, const void* __restrict__ Mi,
    const void* __restrict__ stf, const void* __restrict__ Mf,
    const void* __restrict__ Wq, const void* __restrict__ bq,
    const void* __restrict__ Wk, const void* __restrict__ bk,
    const void* __restrict__ Wv, const void* __restrict__ bv,
    const void* __restrict__ Wg, const void* __restrict__ bg,
    float* __restrict__ fu, float* __restrict__ fphi,
    __bf16* __restrict__ fQ, __bf16* __restrict__ fK,
    __bf16* __restrict__ fV, __bf16* __restrict__ fG,
    const int* __restrict__ flagp)
{
    const int bf = *flagp;
    const int job = blockIdx.z;
    const void* A = x; const void* Bw; const void* bias = nullptr;
    int Kd = 512, act = 0; bool trb = true;
    float* of = nullptr; __bf16* ob = nullptr;
    switch (job) {
        case 0: Bw = Mi; trb = false; of = fu; break;
        case 1: Bw = Wq; bias = bq; act = 1; ob = fQ; break;
        case 2: Bw = Wk; bias = bk; act = 1; ob = fK; break;
        case 3: Bw = Wv; bias = bv; act = 1; ob = fV; break;
        case 4: Bw = Wg; bias = bg; act = 2; ob = fG; break;
        default: A = stf; Bw = Mf; trb = false; of = fphi; Kd = 32; break;
    }
    const int M = (job == 5) ? 1024 : 2048;
    const int m0 = blockIdx.y * 64;
    if (m0 >= M) return;
    const int n0 = blockIdx.x * 64;

    __shared__ __align__(16) __bf16 As[64][40];
    __shared__ __align__(16) __bf16 Bs[64][40];
    const int tid = threadIdx.x;
    const int wave = tid >> 6, lane = tid & 63;
    const int lm = lane & 15, kq = lane >> 4;

    f32x4 acc[4] = {{0.f,0.f,0.f,0.f},{0.f,0.f,0.f,0.f},
                    {0.f,0.f,0.f,0.f},{0.f,0.f,0.f,0.f}};

    for (int k0 = 0; k0 < Kd; k0 += 32) {
        if (k0) __syncthreads();
        {
            const int mo = tid >> 2;
            const int ko = (tid & 3) * 8;
            if (job == 5) {
                #pragma unroll
                for (int q = 0; q < 8; ++q) {
                    const int k = ko + q;
                    As[mo][k] = (k < 24) ? (__bf16)ldin(A, (size_t)(m0 + mo) * 24 + k, bf)
                                         : (__bf16)0.f;
                }
            } else {
                const size_t off = (size_t)(m0 + mo) * 512 + k0 + ko;
                if (bf) {
                    *(bf16x8*)&As[mo][ko] = *(const bf16x8*)((const __bf16*)A + off);
                } else {
                    const float* Af = (const float*)A + off;
                    const float4 f0 = *(const float4*)Af;
                    const float4 f1 = *(const float4*)(Af + 4);
                    bf16x8 t;
                    t[0]=(__bf16)f0.x; t[1]=(__bf16)f0.y; t[2]=(__bf16)f0.z; t[3]=(__bf16)f0.w;
                    t[4]=(__bf16)f1.x; t[5]=(__bf16)f1.y; t[6]=(__bf16)f1.z; t[7]=(__bf16)f1.w;
                    *(bf16x8*)&As[mo][ko] = t;
                }
            }
        }
        if (trb) {
            const int no = tid >> 2;
            const int ko = (tid & 3) * 8;
            const size_t off = (size_t)(n0 + no) * 512 + k0 + ko;
            if (bf) {
                *(bf16x8*)&Bs[no][ko] = *(const bf16x8*)((const __bf16*)Bw + off);
            } else {
                const float* Bf = (const float*)Bw + off;
                const float4 f0 = *(const float4*)Bf;
                const float4 f1 = *(const float4*)(Bf + 4);
                bf16x8 t;
                t[0]=(__bf16)f0.x; t[1]=(__bf16)f0.y; t[2]=(__bf16)f0.z; t[3]=(__bf16)f0.w;
                t[4]=(__bf16)f1.x; t[5]=(__bf16)f1.y; t[6]=(__bf16)f1.z; t[7]=(__bf16)f1.w;
                *(bf16x8*)&Bs[no][ko] = t;
            }
        } else {
            const int kk = tid >> 3;
            const int nn = (tid & 7) * 8;
            if (job == 5) {
                #pragma unroll
                for (int q = 0; q < 8; ++q)
                    Bs[nn + q][kk] = (kk < 24) ? (__bf16)ldin(Bw, (size_t)kk * 512 + n0 + nn + q, bf)
                                               : (__bf16)0.f;
            } else {
                const size_t off = (size_t)(k0 + kk) * 512 + n0 + nn;
                if (bf) {
                    const bf16x8 t = *(const bf16x8*)((const __bf16*)Bw + off);
                    #pragma unroll
                    for (int q = 0; q < 8; ++q) Bs[nn + q][kk] = t[q];
                } else {
                    const float* Bf = (const float*)Bw + off;
                    #pragma unroll
                    for (int q = 0; q < 8; ++q) Bs[nn + q][kk] = (__bf16)Bf[q];
                }
            }
        }
        __syncthreads();
        const bf16x8 a = *(const bf16x8*)&As[wave * 16 + lm][kq * 8];
        #pragma unroll
        for (int nt = 0; nt < 4; ++nt) {
            const bf16x8 b = *(const bf16x8*)&Bs[nt * 16 + lm][kq * 8];
            acc[nt] = __builtin_amdgcn_mfma_f32_16x16x32_bf16(a, b, acc[nt], 0, 0, 0);
        }
    }
    #pragma unroll
    for (int nt = 0; nt < 4; ++nt) {
        const int n = n0 + nt * 16 + lm;
        #pragma unroll
        for (int r2 = 0; r2 < 4; ++r2) {
            const int m = m0 + wave * 16 + kq * 4 + r2;
            float v = acc[nt][r2];
            if (bias) v += ldin(bias, (size_t)n, bf);
            if (act == 1) v = gelu_f(v);
            if (act == 2) v = 1.f / (1.f + expf(-v));
            if (of) of[(size_t)m * 512 + n] = v;
            else    ob[(size_t)m * 512 + n] = (__bf16)v;
        }
    }
}

// -------- lag-chunked even-lag causal conv, bf16 partials --------
// chunk c handles lag-tiles j in {c, c+4, ...} with j <= ti (diag owned by
// chunk ti&3 naturally). Every block writes its full 64x64 output region of
// partial c (zeros if no tiles) -- required, ws is poisoned.
__global__ __launch_bounds__(256) void conv_tile_k(const float* __restrict__ u,
                                                   const float* __restrict__ v,
                                                   __bf16* __restrict__ wp)
{
    __shared__ float vs[64][64];
    __shared__ float us[128][64];
    const int tid = threadIdx.x;
    const int rl = tid & 63;
    const int tg = tid >> 6;
    const int ti = blockIdx.x;
    const int t0 = ti * 64;
    const int r0 = blockIdx.y * 64;
    const int b  = blockIdx.z >> 2;
    const int c  = blockIdx.z & 3;
    const float* ub = u + (size_t)b * T_SEQ * R_DIM;

    float acc[16] = {};

    for (int j = c; j <= ti; j += 4) {
        if (j != c) __syncthreads();
        const int L0 = j * 64;
        const int W0 = t0 - L0 - 63;
        #pragma unroll
        for (int jj = 0; jj < 8; ++jj) {
            const int n = jj * 256 + tid;
            const int row = n >> 4, c4 = (n & 15) * 4;
            int s = W0 + row;
            s = s < 0 ? 0 : (s > T_SEQ - 1 ? T_SEQ - 1 : s);
            *(float4*)&us[row][c4] = *(const float4*)&ub[(size_t)s * R_DIM + r0 + c4];
        }
        #pragma unroll
        for (int jj = 0; jj < 4; ++jj) {
            const int n = jj * 256 + tid;
            const int row = n >> 4, c4 = (n & 15) * 4;
            *(float4*)&vs[row][c4] = *(const float4*)&v[(size_t)(L0 + row) * R_DIM + r0 + c4];
        }
        __syncthreads();

        if (j < ti) {
            #pragma unroll
            for (int g = 0; g < 4; ++g) {
                const int wsmin = tg * 16 + 49 - 16 * g;
                float ur[30];
                #pragma unroll
                for (int q = 0; q < 30; ++q) ur[q] = us[wsmin + q][rl];
                float vr[8];
                #pragma unroll
                for (int e = 0; e < 8; ++e) vr[e] = vs[16 * g + 2 * e][rl];
                #pragma unroll
                for (int e = 0; e < 8; ++e)
                    #pragma unroll
                    for (int i = 0; i < 16; ++i)
                        acc[i] += vr[e] * ur[i - 2 * e + 14];
            }
        } else {
            for (int l = 0; l < 64; l += 2) {
                const float vv = vs[l][rl];
                #pragma unroll
                for (int i = 0; i < 16; ++i) {
                    const int srel = tg * 16 + i - l;
                    if (srel >= 0) acc[i] += vv * us[srel + 63][rl];
                }
            }
        }
    }
    __bf16* wout = wp + (size_t)c * (BATCH * T_SEQ * R_DIM);
    #pragma unroll
    for (int i = 0; i < 16; ++i)
        wout[((size_t)b * T_SEQ + t0 + tg * 16 + i) * R_DIM + r0 + rl] = (__bf16)(2.f * acc[i]);
}

// layernorm over last dim (512), fused 4-partial reduce; writes fp32 x_tilde
__global__ __launch_bounds__(256) void ln_k(const __bf16* __restrict__ wp,
                                            float* __restrict__ xt,
                                            const void* __restrict__ g,
                                            const void* __restrict__ b,
                                            const int* __restrict__ flagp)
{
    const int bf = *flagp;
    const size_t row = (size_t)blockIdx.y * T_SEQ + blockIdx.x;
    const int tid = threadIdx.x;
    const size_t PSZ = (size_t)BATCH * T_SEQ * R_DIM;
    float x0 = 0.f, x1 = 0.f;
    #pragma unroll
    for (int cc = 0; cc < 4; ++cc) {
        x0 += __bfloat162float(((const __hip_bfloat16*)wp)[cc * PSZ + row * R_DIM + tid]);
        x1 += __bfloat162float(((const __hip_bfloat16*)wp)[cc * PSZ + row * R_DIM + tid + 256]);
    }
    __shared__ float red[4];
    float s = x0 + x1;
    #pragma unroll
    for (int off = 32; off > 0; off >>= 1) s += __shfl_down(s, off, 64);
    if ((tid & 63) == 0) red[tid >> 6] = s;
    __syncthreads();
    const float mu = (red[0] + red[1] + red[2] + red[3]) * (1.f / 512.f);
    __syncthreads();
    const float d0 = x0 - mu, d1 = x1 - mu;
    float vsum = d0 * d0 + d1 * d1;
    #pragma unroll
    for (int off = 32; off > 0; off >>= 1) vsum += __shfl_down(vsum, off, 64);
    if ((tid & 63) == 0) red[tid >> 6] = vsum;
    __syncthreads();
    const float var = (red[0] + red[1] + red[2] + red[3]) * (1.f / 512.f);
    const float rs = rsqrtf(var + 1e-5f);
    float* p = xt + row * R_DIM;
    p[tid]       = d0 * rs * ldin(g, tid, bf)       + ldin(b, tid, bf);
    p[tid + 256] = d1 * rs * ldin(g, tid + 256, bf) + ldin(b, tid + 256, bf);
}

// ---------------- MFMA attention, s-chunked: Y_c = partial tril(Q V^T) K ----
__global__ __launch_bounds__(256) void attn_mfma(const __bf16* __restrict__ Q,
                                                 const __bf16* __restrict__ K,
                                                 const __bf16* __restrict__ V,
                                                 float* __restrict__ Y0,
                                                 float* __restrict__ Y1)
{
    __shared__ __align__(16) __bf16 Qs[64][72];
    __shared__ __align__(16) __bf16 Vs[64][72];
    __shared__ __align__(16) __bf16 Kt[64][72];
    __shared__ __align__(16) __bf16 Sa[64][72];
    const int tid = threadIdx.x;
    const int wave = tid >> 6, lane = tid & 63;
    const int lm = lane & 15, kq = lane >> 4;
    const int ti = blockIdx.x;
    const int t0 = ti * 64;
    const int h = blockIdx.y;
    const int b = blockIdx.z >> 1;
    const int c = blockIdx.z & 1;
    const size_t cbase = ((size_t)b * T_SEQ) * D_MOD + h * HDIM;

    #pragma unroll
    for (int it = 0; it < 2; ++it) {
        const int n = it * 256 + tid;
        const int row = n >> 3, p0 = (n & 7) * 8;
        *(bf16x8*)&Qs[row][p0] = *(const bf16x8*)&Q[cbase + (size_t)(t0 + row) * D_MOD + p0];
    }
    f32x4 accY[4] = {{0.f,0.f,0.f,0.f},{0.f,0.f,0.f,0.f},
                     {0.f,0.f,0.f,0.f},{0.f,0.f,0.f,0.f}};

    for (int j = c; j <= ti; j += 2) {
        __syncthreads();
        const int s0 = j * 64;
        #pragma unroll
        for (int it = 0; it < 2; ++it) {
            const int n = it * 256 + tid;
            const int row = n >> 3, c0 = (n & 7) * 8;
            *(bf16x8*)&Vs[row][c0] = *(const bf16x8*)&V[cbase + (size_t)(s0 + row) * D_MOD + c0];
            const bf16x8 kv = *(const bf16x8*)&K[cbase + (size_t)(s0 + row) * D_MOD + c0];
            #pragma unroll
            for (int q = 0; q < 8; ++q) Kt[c0 + q][row] = kv[q];
        }
        __syncthreads();
        f32x4 sacc[4] = {{0.f,0.f,0.f,0.f},{0.f,0.f,0.f,0.f},
                         {0.f,0.f,0.f,0.f},{0.f,0.f,0.f,0.f}};
        #pragma unroll
        for (int ks = 0; ks < 2; ++ks) {
            const bf16x8 a = *(const bf16x8*)&Qs[wave * 16 + lm][ks * 32 + kq * 8];
            #pragma unroll
            for (int nt = 0; nt < 4; ++nt) {
                const bf16x8 bb = *(const bf16x8*)&Vs[nt * 16 + lm][ks * 32 + kq * 8];
                sacc[nt] = __builtin_amdgcn_mfma_f32_16x16x32_bf16(a, bb, sacc[nt], 0, 0, 0);
            }
        }
        const bool diag = (j == ti);
        #pragma unroll
        for (int nt = 0; nt < 4; ++nt) {
            const int sl = nt * 16 + lm;
            #pragma unroll
            for (int r2 = 0; r2 < 4; ++r2) {
                const int tl = wave * 16 + kq * 4 + r2;
                float v = sacc[nt][r2];
                if (diag && sl > tl) v = 0.f;
                Sa[tl][sl] = (__bf16)v;
            }
        }
        #pragma unroll
        for (int ks = 0; ks < 2; ++ks) {
            const bf16x8 a = *(const bf16x8*)&Sa[wave * 16 + lm][ks * 32 + kq * 8];
            #pragma unroll
            for (int nt = 0; nt < 4; ++nt) {
                const bf16x8 bb = *(const bf16x8*)&Kt[nt * 16 + lm][ks * 32 + kq * 8];
                accY[nt] = __builtin_amdgcn_mfma_f32_16x16x32_bf16(a, bb, accY[nt], 0, 0, 0);
            }
        }
    }
    float* Yp = c ? Y1 : Y0;
    #pragma unroll
    for (int nt = 0; nt < 4; ++nt) {
        const int nh = nt * 16 + lm;
        #pragma unroll
        for (int r2 = 0; r2 < 4; ++r2) {
            const int tl = wave * 16 + kq * 4 + r2;
            Yp[cbase + (size_t)(t0 + tl) * D_MOD + nh] = accY[nt][r2];
        }
    }
}

// ---------------- final GEMM with fused comb: out = (g*(y0+y1)+(1-g)*xt) @ Wo^T + bo
__global__ __launch_bounds__(256) void final_gemm(const __bf16* __restrict__ G,
                                                  const float* __restrict__ Ya,
                                                  const float* __restrict__ Yb2,
                                                  const float* __restrict__ Xt,
                                                  const void* __restrict__ Wo,
                                                  const void* __restrict__ bo,
                                                  void* __restrict__ out,
                                                  const int* __restrict__ flagp)
{
    const int bf = *flagp;
    __shared__ __align__(16) __bf16 As[64][40];
    __shared__ __align__(16) __bf16 Bs[64][40];
    const int tid = threadIdx.x;
    const int wave = tid >> 6, lane = tid & 63;
    const int lm = lane & 15, kq = lane >> 4;
    const int m0 = blockIdx.y * 64, n0 = blockIdx.x * 64;

    f32x4 acc[4] = {{0.f,0.f,0.f,0.f},{0.f,0.f,0.f,0.f},
                    {0.f,0.f,0.f,0.f},{0.f,0.f,0.f,0.f}};

    for (int k0 = 0; k0 < 512; k0 += 32) {
        if (k0) __syncthreads();
        {
            const int mo = tid >> 2;
            const int ko = (tid & 3) * 8;
            const size_t off = (size_t)(m0 + mo) * 512 + k0 + ko;
            const bf16x8 g8 = *(const bf16x8*)(G + off);
            const float4 ya0 = *(const float4*)(Ya + off);
            const float4 ya1 = *(const float4*)(Ya + off + 4);
            const float4 yb0 = *(const float4*)(Yb2 + off);
            const float4 yb1 = *(const float4*)(Yb2 + off + 4);
            const float4 x0 = *(const float4*)(Xt + off);
            const float4 x1 = *(const float4*)(Xt + off + 4);
            const float yv[8] = {ya0.x+yb0.x, ya0.y+yb0.y, ya0.z+yb0.z, ya0.w+yb0.w,
                                 ya1.x+yb1.x, ya1.y+yb1.y, ya1.z+yb1.z, ya1.w+yb1.w};
            const float xv[8] = {x0.x,x0.y,x0.z,x0.w,x1.x,x1.y,x1.z,x1.w};
            bf16x8 t;
            #pragma unroll
            for (int q = 0; q < 8; ++q) {
                const float gg = (float)g8[q];
                t[q] = (__bf16)(gg * yv[q] + (1.f - gg) * xv[q]);
            }
            *(bf16x8*)&As[mo][ko] = t;
        }
        {
            const int no = tid >> 2;
            const int ko = (tid & 3) * 8;
            const size_t off = (size_t)(n0 + no) * 512 + k0 + ko;
            if (bf) {
                *(bf16x8*)&Bs[no][ko] = *(const bf16x8*)((const __bf16*)Wo + off);
            } else {
                const float* Bf = (const float*)Wo + off;
                const float4 f0 = *(const float4*)Bf;
                const float4 f1 = *(const float4*)(Bf + 4);
                bf16x8 t;
                t[0]=(__bf16)f0.x; t[1]=(__bf16)f0.y; t[2]=(__bf16)f0.z; t[3]=(__bf16)f0.w;
                t[4]=(__bf16)f1.x; t[5]=(__bf16)f1.y; t[6]=(__bf16)f1.z; t[7]=(__bf16)f1.w;
                *(bf16x8*)&Bs[no][ko] = t;
            }
        }
        __syncthreads();
        const bf16x8 a = *(const bf16x8*)&As[wave * 16 + lm][kq * 8];
        #pragma unroll
        for (int nt = 0; nt < 4; ++nt) {
            const bf16x8 b = *(const bf16x8*)&Bs[nt * 16 + lm][kq * 8];
            acc[nt] = __builtin_amdgcn_mfma_f32_16x16x32_bf16(a, b, acc[nt], 0, 0, 0);
        }
    }
    #pragma unroll
    for (int nt = 0; nt < 4; ++nt) {
        const int n = n0 + nt * 16 + lm;
        #pragma unroll
        for (int r2 = 0; r2 < 4; ++r2) {
            const int m = m0 + wave * 16 + kq * 4 + r2;
            float v = acc[nt][r2] + ldin(bo, (size_t)n, bf);
            stout(out, (size_t)m * 512 + n, bf, v);
        }
    }
}

extern "C" void kernel_launch(void* const* d_in, const int* in_sizes, int n_in,
                              void* d_out, int out_size, void* d_ws, size_t ws_size,
                              hipStream_t stream)
{
    const void* x   = d_in[0];
    const void* stf = d_in[1];
    const void* Mi  = d_in[2];
    const void* Mf  = d_in[3];
    const void* Wq  = d_in[4];  const void* bq = d_in[5];
    const void* Wk  = d_in[6];  const void* bk = d_in[7];
    const void* Wv  = d_in[8];  const void* bv = d_in[9];
    const void* Wg  = d_in[10]; const void* bg = d_in[11];
    const void* Wo  = d_in[12]; const void* bo = d_in[13];
    const void* lnw = d_in[14]; const void* lnb = d_in[15];

    int*   flag  = (int*)d_ws;
    float* base  = (float*)d_ws + 64;
    float*  f_u   = base;                        // u_proj; reused as Y0 after conv
    float*  f_phi = base + 1048576;              // phi (1024x512 fp32)
    float*  f_w   = base + 1572864;              // x_tilde fp32
    __bf16* f_wp  = (__bf16*)(base + 2621440);   // 4 conv partials, bf16, 2MB each
    float*  f_Y1  = base + 2621440;              // overlays partials 0-1 (free post-ln)
    __bf16* f_Q   = (__bf16*)(base + 4718592);   // bf16 2048x512 each
    __bf16* f_K   = f_Q + 1048576;
    __bf16* f_V   = f_K + 1048576;
    __bf16* f_G   = f_V + 1048576;
    // total ws: 256B + 26MB

    dim3 blk(256);

    detect_k<<<1, blk, 0, stream>>>(x, flag);

    mega_gemm<<<dim3(8, 32, 6), blk, 0, stream>>>(
        x, Mi, stf, Mf, Wq, bq, Wk, bk, Wv, bv, Wg, bg,
        f_u, f_phi, f_Q, f_K, f_V, f_G, flag);

    conv_tile_k<<<dim3(T_SEQ / 64, R_DIM / 64, BATCH * 4), blk, 0, stream>>>(f_u, f_phi, f_wp);
    ln_k<<<dim3(T_SEQ, BATCH), blk, 0, stream>>>(f_wp, f_w, lnw, lnb, flag);

    attn_mfma<<<dim3(T_SEQ / 64, NHEAD, BATCH * 2), blk, 0, stream>>>(f_Q, f_K, f_V, f_u, f_Y1);

    final_gemm<<<dim3(8, 32), blk, 0, stream>>>(f_G, f_u, f_Y1, f_w, Wo, bo, d_out, flag);
}

// Round 6
// 211.401 us; speedup vs baseline: 3.4668x; 1.0047x over previous
//
#include <hip/hip_runtime.h>
#include <hip/hip_bf16.h>

#define T_SEQ 1024
#define D_MOD 512
#define NHEAD 8
#define HDIM  64
#define R_DIM 512
#define BATCH 2

typedef __attribute__((ext_vector_type(8))) __bf16 bf16x8;
typedef __attribute__((ext_vector_type(4))) float f32x4;

// runtime-dtype load/store: bf==1 -> bf16, bf==0 -> fp32 (wave-uniform branch)
__device__ __forceinline__ float ldin(const void* p, size_t i, int bf) {
    if (bf) return __bfloat162float(((const __hip_bfloat16*)p)[i]);
    return ((const float*)p)[i];
}
__device__ __forceinline__ void stout(void* p, size_t i, int bf, float v) {
    if (bf) ((__hip_bfloat16*)p)[i] = __float2bfloat16(v);
    else    ((float*)p)[i] = v;
}

__device__ __forceinline__ float gelu_f(float x) {
    return 0.5f * x * (1.f + tanhf(0.7978845608028654f * (x + 0.044715f * x * x * x)));
}

// dtype sniffing: fp32 N(0,1) data has ~0.4% of 16-bit halves matching bf16
// inf/nan exponent; true bf16 data has none. flag=1 -> bf16.
__global__ __launch_bounds__(256) void detect_k(const void* __restrict__ x,
                                                int* __restrict__ flag)
{
    __shared__ int cnt;
    if (threadIdx.x == 0) cnt = 0;
    __syncthreads();
    const unsigned short* h = (const unsigned short*)x;
    int c = 0;
    for (int i = threadIdx.x; i < 8192; i += 256) {
        unsigned short v = h[i];
        if ((v & 0x7F80u) == 0x7F80u) c++;
    }
    atomicAdd(&cnt, c);
    __syncthreads();
    if (threadIdx.x == 0) *flag = (cnt == 0) ? 1 : 0;
}

// zero n4 float4's starting at p (ws is poisoned 0xAA before every launch)
__global__ __launch_bounds__(256) void zero_k(float4* __restrict__ p, int n4)
{
    const int i = blockIdx.x * 256 + threadIdx.x;
    if (i < n4) p[i] = make_float4(0.f, 0.f, 0.f, 0.f);
}

// ---------------- fused projection GEMMs, one dispatch ----------------
__global__ __launch_bounds__(256) void mega_gemm(
    const void* __restrict__ x, const void* __restrict__ Mi,
    const void* __restrict__ stf, const void* __restrict__ Mf,
    const void* __restrict__ Wq, const void* __restrict__ bq,
    const void* __restrict__ Wk, const void* __restrict__ bk,
    const void* __restrict__ Wv, const void* __restrict__ bv,
    const void* __restrict__ Wg, const void* __restrict__ bg,
    float* __restrict__ fu, float* __restrict__ fphi,
    __bf16* __restrict__ fQ, __bf16* __restrict__ fK,
    __bf16* __restrict__ fV, __bf16* __restrict__ fG,
    const int* __restrict__ flagp)
{
    const int bf = *flagp;
    const int job = blockIdx.z;
    const void* A = x; const void* Bw; const void* bias = nullptr;
    int Kd = 512, act = 0; bool trb = true;
    float* of = nullptr; __bf16* ob = nullptr;
    switch (job) {
        case 0: Bw = Mi; trb = false; of = fu; break;
        case 1: Bw = Wq; bias = bq; act = 1; ob = fQ; break;
        case 2: Bw = Wk; bias = bk; act = 1; ob = fK; break;
        case 3: Bw = Wv; bias = bv; act = 1; ob = fV; break;
        case 4: Bw = Wg; bias = bg; act = 2; ob = fG; break;
        default: A = stf; Bw = Mf; trb = false; of = fphi; Kd = 32; break;
    }
    const int M = (job == 5) ? 1024 : 2048;
    const int m0 = blockIdx.y * 64;
    if (m0 >= M) return;
    const int n0 = blockIdx.x * 64;

    __shared__ __align__(16) __bf16 As[64][40];
    __shared__ __align__(16) __bf16 Bs[64][40];
    const int tid = threadIdx.x;
    const int wave = tid >> 6, lane = tid & 63;
    const int lm = lane & 15, kq = lane >> 4;

    f32x4 acc[4] = {{0.f,0.f,0.f,0.f},{0.f,0.f,0.f,0.f},
                    {0.f,0.f,0.f,0.f},{0.f,0.f,0.f,0.f}};

    for (int k0 = 0; k0 < Kd; k0 += 32) {
        if (k0) __syncthreads();
        {
            const int mo = tid >> 2;
            const int ko = (tid & 3) * 8;
            if (job == 5) {
                #pragma unroll
                for (int q = 0; q < 8; ++q) {
                    const int k = ko + q;
                    As[mo][k] = (k < 24) ? (__bf16)ldin(A, (size_t)(m0 + mo) * 24 + k, bf)
                                         : (__bf16)0.f;
                }
            } else {
                const size_t off = (size_t)(m0 + mo) * 512 + k0 + ko;
                if (bf) {
                    *(bf16x8*)&As[mo][ko] = *(const bf16x8*)((const __bf16*)A + off);
                } else {
                    const float* Af = (const float*)A + off;
                    const float4 f0 = *(const float4*)Af;
                    const float4 f1 = *(const float4*)(Af + 4);
                    bf16x8 t;
                    t[0]=(__bf16)f0.x; t[1]=(__bf16)f0.y; t[2]=(__bf16)f0.z; t[3]=(__bf16)f0.w;
                    t[4]=(__bf16)f1.x; t[5]=(__bf16)f1.y; t[6]=(__bf16)f1.z; t[7]=(__bf16)f1.w;
                    *(bf16x8*)&As[mo][ko] = t;
                }
            }
        }
        if (trb) {
            const int no = tid >> 2;
            const int ko = (tid & 3) * 8;
            const size_t off = (size_t)(n0 + no) * 512 + k0 + ko;
            if (bf) {
                *(bf16x8*)&Bs[no][ko] = *(const bf16x8*)((const __bf16*)Bw + off);
            } else {
                const float* Bf = (const float*)Bw + off;
                const float4 f0 = *(const float4*)Bf;
                const float4 f1 = *(const float4*)(Bf + 4);
                bf16x8 t;
                t[0]=(__bf16)f0.x; t[1]=(__bf16)f0.y; t[2]=(__bf16)f0.z; t[3]=(__bf16)f0.w;
                t[4]=(__bf16)f1.x; t[5]=(__bf16)f1.y; t[6]=(__bf16)f1.z; t[7]=(__bf16)f1.w;
                *(bf16x8*)&Bs[no][ko] = t;
            }
        } else {
            const int kk = tid >> 3;
            const int nn = (tid & 7) * 8;
            if (job == 5) {
                #pragma unroll
                for (int q = 0; q < 8; ++q)
                    Bs[nn + q][kk] = (kk < 24) ? (__bf16)ldin(Bw, (size_t)kk * 512 + n0 + nn + q, bf)
                                               : (__bf16)0.f;
            } else {
                const size_t off = (size_t)(k0 + kk) * 512 + n0 + nn;
                if (bf) {
                    const bf16x8 t = *(const bf16x8*)((const __bf16*)Bw + off);
                    #pragma unroll
                    for (int q = 0; q < 8; ++q) Bs[nn + q][kk] = t[q];
                } else {
                    const float* Bf = (const float*)Bw + off;
                    #pragma unroll
                    for (int q = 0; q < 8; ++q) Bs[nn + q][kk] = (__bf16)Bf[q];
                }
            }
        }
        __syncthreads();
        const bf16x8 a = *(const bf16x8*)&As[wave * 16 + lm][kq * 8];
        #pragma unroll
        for (int nt = 0; nt < 4; ++nt) {
            const bf16x8 b = *(const bf16x8*)&Bs[nt * 16 + lm][kq * 8];
            acc[nt] = __builtin_amdgcn_mfma_f32_16x16x32_bf16(a, b, acc[nt], 0, 0, 0);
        }
    }
    #pragma unroll
    for (int nt = 0; nt < 4; ++nt) {
        const int n = n0 + nt * 16 + lm;
        #pragma unroll
        for (int r2 = 0; r2 < 4; ++r2) {
            const int m = m0 + wave * 16 + kq * 4 + r2;
            float v = acc[nt][r2];
            if (bias) v += ldin(bias, (size_t)n, bf);
            if (act == 1) v = gelu_f(v);
            if (act == 2) v = 1.f / (1.f + expf(-v));
            if (of) of[(size_t)m * 512 + n] = v;
            else    ob[(size_t)m * 512 + n] = (__bf16)v;
        }
    }
}

// ---------------- fused uniform-task conv + attention ----------------
// blockIdx.x = flat (ti, j<=ti) pair in [0,136); z<2: conv (b=z, y=r-tile);
// z>=2: attn (b=z-2, y=head). One tile-task per block, fp32 atomicAdd out.
__global__ __launch_bounds__(256) void conv_attn_k(
    const float* __restrict__ u, const float* __restrict__ vphi,
    float* __restrict__ w,
    const __bf16* __restrict__ Q, const __bf16* __restrict__ K,
    const __bf16* __restrict__ V, float* __restrict__ Y)
{
    __shared__ __align__(16) unsigned char smem[49152];
    const int tid = threadIdx.x;
    const int z = blockIdx.z;
    // decode flat task -> (ti, j)
    const int k = blockIdx.x;
    int ti = (int)((sqrtf(8.f * k + 1.f) - 1.f) * 0.5f);
    while ((ti + 1) * (ti + 2) / 2 <= k) ++ti;
    while (ti * (ti + 1) / 2 > k) --ti;
    const int j = k - ti * (ti + 1) / 2;
    const int t0 = ti * 64, L0 = j * 64;

    if (z < 2) {
        // ---- conv tile: w[b, t0:t0+64, r0:r0+64] += contribution of lag tile j
        float (*vs)[64] = (float (*)[64])smem;            // 16 KB
        float (*us)[64] = (float (*)[64])(smem + 16384);  // 32 KB
        const int rl = tid & 63, tg = tid >> 6;
        const int b = z;
        const int r0 = blockIdx.y * 64;
        const float* ub = u + (size_t)b * T_SEQ * R_DIM;
        const int W0 = t0 - L0 - 63;
        #pragma unroll
        for (int jj = 0; jj < 8; ++jj) {
            const int n = jj * 256 + tid;
            const int row = n >> 4, c4 = (n & 15) * 4;
            int s = W0 + row;
            s = s < 0 ? 0 : (s > T_SEQ - 1 ? T_SEQ - 1 : s);
            *(float4*)&us[row][c4] = *(const float4*)&ub[(size_t)s * R_DIM + r0 + c4];
        }
        #pragma unroll
        for (int jj = 0; jj < 4; ++jj) {
            const int n = jj * 256 + tid;
            const int row = n >> 4, c4 = (n & 15) * 4;
            *(float4*)&vs[row][c4] = *(const float4*)&vphi[(size_t)(L0 + row) * R_DIM + r0 + c4];
        }
        __syncthreads();
        float acc[16] = {};
        if (j < ti) {
            #pragma unroll
            for (int g = 0; g < 4; ++g) {
                const int wsmin = tg * 16 + 49 - 16 * g;
                float ur[30];
                #pragma unroll
                for (int q = 0; q < 30; ++q) ur[q] = us[wsmin + q][rl];
                float vr[8];
                #pragma unroll
                for (int e = 0; e < 8; ++e) vr[e] = vs[16 * g + 2 * e][rl];
                #pragma unroll
                for (int e = 0; e < 8; ++e)
                    #pragma unroll
                    for (int i = 0; i < 16; ++i)
                        acc[i] += vr[e] * ur[i - 2 * e + 14];
            }
        } else {
            for (int l = 0; l < 64; l += 2) {
                const float vv = vs[l][rl];
                #pragma unroll
                for (int i = 0; i < 16; ++i) {
                    const int srel = tg * 16 + i - l;
                    if (srel >= 0) acc[i] += vv * us[srel + 63][rl];
                }
            }
        }
        #pragma unroll
        for (int i = 0; i < 16; ++i)
            atomicAdd(&w[((size_t)b * T_SEQ + t0 + tg * 16 + i) * R_DIM + r0 + rl],
                      2.f * acc[i]);
    } else {
        // ---- attn tile: Y[b,h,t-tile ti] += tril-masked (Q V^T)(tile j) K
        __bf16 (*Qs)[72] = (__bf16 (*)[72])smem;              // 9216 B
        __bf16 (*Vs)[72] = (__bf16 (*)[72])(smem + 9216);
        __bf16 (*Kt)[72] = (__bf16 (*)[72])(smem + 18432);
        __bf16 (*Sa)[72] = (__bf16 (*)[72])(smem + 27648);
        const int wave = tid >> 6, lane = tid & 63;
        const int lm = lane & 15, kq = lane >> 4;
        const int b = z - 2;
        const int h = blockIdx.y;
        const size_t cbase = ((size_t)b * T_SEQ) * D_MOD + h * HDIM;
        #pragma unroll
        for (int it = 0; it < 2; ++it) {
            const int n = it * 256 + tid;
            const int row = n >> 3, p0 = (n & 7) * 8;
            *(bf16x8*)&Qs[row][p0] = *(const bf16x8*)&Q[cbase + (size_t)(t0 + row) * D_MOD + p0];
            *(bf16x8*)&Vs[row][p0] = *(const bf16x8*)&V[cbase + (size_t)(L0 + row) * D_MOD + p0];
            const bf16x8 kv = *(const bf16x8*)&K[cbase + (size_t)(L0 + row) * D_MOD + p0];
            #pragma unroll
            for (int q = 0; q < 8; ++q) Kt[p0 + q][row] = kv[q];
        }
        __syncthreads();
        f32x4 sacc[4] = {{0.f,0.f,0.f,0.f},{0.f,0.f,0.f,0.f},
                         {0.f,0.f,0.f,0.f},{0.f,0.f,0.f,0.f}};
        #pragma unroll
        for (int ks = 0; ks < 2; ++ks) {
            const bf16x8 a = *(const bf16x8*)&Qs[wave * 16 + lm][ks * 32 + kq * 8];
            #pragma unroll
            for (int nt = 0; nt < 4; ++nt) {
                const bf16x8 bb = *(const bf16x8*)&Vs[nt * 16 + lm][ks * 32 + kq * 8];
                sacc[nt] = __builtin_amdgcn_mfma_f32_16x16x32_bf16(a, bb, sacc[nt], 0, 0, 0);
            }
        }
        // mask + stash S bf16 in own wave's 16-row strip (no barrier needed:
        // wave w writes rows [16w,16w+16) and reads only those rows below)
        const bool diag = (j == ti);
        #pragma unroll
        for (int nt = 0; nt < 4; ++nt) {
            const int sl = nt * 16 + lm;
            #pragma unroll
            for (int r2 = 0; r2 < 4; ++r2) {
                const int tl = wave * 16 + kq * 4 + r2;
                float v = sacc[nt][r2];
                if (diag && sl > tl) v = 0.f;
                Sa[tl][sl] = (__bf16)v;
            }
        }
        f32x4 accY[4] = {{0.f,0.f,0.f,0.f},{0.f,0.f,0.f,0.f},
                         {0.f,0.f,0.f,0.f},{0.f,0.f,0.f,0.f}};
        #pragma unroll
        for (int ks = 0; ks < 2; ++ks) {
            const bf16x8 a = *(const bf16x8*)&Sa[wave * 16 + lm][ks * 32 + kq * 8];
            #pragma unroll
            for (int nt = 0; nt < 4; ++nt) {
                const bf16x8 bb = *(const bf16x8*)&Kt[nt * 16 + lm][ks * 32 + kq * 8];
                accY[nt] = __builtin_amdgcn_mfma_f32_16x16x32_bf16(a, bb, accY[nt], 0, 0, 0);
            }
        }
        #pragma unroll
        for (int nt = 0; nt < 4; ++nt) {
            const int nh = nt * 16 + lm;
            #pragma unroll
            for (int r2 = 0; r2 < 4; ++r2) {
                const int tl = wave * 16 + kq * 4 + r2;
                atomicAdd(&Y[cbase + (size_t)(t0 + tl) * D_MOD + nh], accY[nt][r2]);
            }
        }
    }
}

// in-place layernorm over last dim (512), fp32 buffer
__global__ __launch_bounds__(256) void ln_k(float* __restrict__ w,
                                            const void* __restrict__ g,
                                            const void* __restrict__ b,
                                            const int* __restrict__ flagp)
{
    const int bf = *flagp;
    const size_t row = (size_t)blockIdx.y * T_SEQ + blockIdx.x;
    float* p = w + row * R_DIM;
    const int tid = threadIdx.x;
    const float x0 = p[tid], x1 = p[tid + 256];
    __shared__ float red[4];
    float s = x0 + x1;
    #pragma unroll
    for (int off = 32; off > 0; off >>= 1) s += __shfl_down(s, off, 64);
    if ((tid & 63) == 0) red[tid >> 6] = s;
    __syncthreads();
    const float mu = (red[0] + red[1] + red[2] + red[3]) * (1.f / 512.f);
    __syncthreads();
    const float d0 = x0 - mu, d1 = x1 - mu;
    float vsum = d0 * d0 + d1 * d1;
    #pragma unroll
    for (int off = 32; off > 0; off >>= 1) vsum += __shfl_down(vsum, off, 64);
    if ((tid & 63) == 0) red[tid >> 6] = vsum;
    __syncthreads();
    const float var = (red[0] + red[1] + red[2] + red[3]) * (1.f / 512.f);
    const float rs = rsqrtf(var + 1e-5f);
    p[tid]       = d0 * rs * ldin(g, tid, bf)       + ldin(b, tid, bf);
    p[tid + 256] = d1 * rs * ldin(g, tid + 256, bf) + ldin(b, tid + 256, bf);
}

// ---------------- final GEMM with fused comb: out = (g*y+(1-g)*xt) @ Wo^T + bo
__global__ __launch_bounds__(256) void final_gemm(const __bf16* __restrict__ G,
                                                  const float* __restrict__ Yf,
                                                  const float* __restrict__ Xt,
                                                  const void* __restrict__ Wo,
                                                  const void* __restrict__ bo,
                                                  void* __restrict__ out,
                                                  const int* __restrict__ flagp)
{
    const int bf = *flagp;
    __shared__ __align__(16) __bf16 As[64][40];
    __shared__ __align__(16) __bf16 Bs[64][40];
    const int tid = threadIdx.x;
    const int wave = tid >> 6, lane = tid & 63;
    const int lm = lane & 15, kq = lane >> 4;
    const int m0 = blockIdx.y * 64, n0 = blockIdx.x * 64;

    f32x4 acc[4] = {{0.f,0.f,0.f,0.f},{0.f,0.f,0.f,0.f},
                    {0.f,0.f,0.f,0.f},{0.f,0.f,0.f,0.f}};

    for (int k0 = 0; k0 < 512; k0 += 32) {
        if (k0) __syncthreads();
        {
            const int mo = tid >> 2;
            const int ko = (tid & 3) * 8;
            const size_t off = (size_t)(m0 + mo) * 512 + k0 + ko;
            const bf16x8 g8 = *(const bf16x8*)(G + off);
            const float4 y0 = *(const float4*)(Yf + off);
            const float4 y1 = *(const float4*)(Yf + off + 4);
            const float4 x0 = *(const float4*)(Xt + off);
            const float4 x1 = *(const float4*)(Xt + off + 4);
            const float yv[8] = {y0.x,y0.y,y0.z,y0.w,y1.x,y1.y,y1.z,y1.w};
            const float xv[8] = {x0.x,x0.y,x0.z,x0.w,x1.x,x1.y,x1.z,x1.w};
            bf16x8 t;
            #pragma unroll
            for (int q = 0; q < 8; ++q) {
                const float gg = (float)g8[q];
                t[q] = (__bf16)(gg * yv[q] + (1.f - gg) * xv[q]);
            }
            *(bf16x8*)&As[mo][ko] = t;
        }
        {
            const int no = tid >> 2;
            const int ko = (tid & 3) * 8;
            const size_t off = (size_t)(n0 + no) * 512 + k0 + ko;
            if (bf) {
                *(bf16x8*)&Bs[no][ko] = *(const bf16x8*)((const __bf16*)Wo + off);
            } else {
                const float* Bf = (const float*)Wo + off;
                const float4 f0 = *(const float4*)Bf;
                const float4 f1 = *(const float4*)(Bf + 4);
                bf16x8 t;
                t[0]=(__bf16)f0.x; t[1]=(__bf16)f0.y; t[2]=(__bf16)f0.z; t[3]=(__bf16)f0.w;
                t[4]=(__bf16)f1.x; t[5]=(__bf16)f1.y; t[6]=(__bf16)f1.z; t[7]=(__bf16)f1.w;
                *(bf16x8*)&Bs[no][ko] = t;
            }
        }
        __syncthreads();
        const bf16x8 a = *(const bf16x8*)&As[wave * 16 + lm][kq * 8];
        #pragma unroll
        for (int nt = 0; nt < 4; ++nt) {
            const bf16x8 b = *(const bf16x8*)&Bs[nt * 16 + lm][kq * 8];
            acc[nt] = __builtin_amdgcn_mfma_f32_16x16x32_bf16(a, b, acc[nt], 0, 0, 0);
        }
    }
    #pragma unroll
    for (int nt = 0; nt < 4; ++nt) {
        const int n = n0 + nt * 16 + lm;
        #pragma unroll
        for (int r2 = 0; r2 < 4; ++r2) {
            const int m = m0 + wave * 16 + kq * 4 + r2;
            float v = acc[nt][r2] + ldin(bo, (size_t)n, bf);
            stout(out, (size_t)m * 512 + n, bf, v);
        }
    }
}

extern "C" void kernel_launch(void* const* d_in, const int* in_sizes, int n_in,
                              void* d_out, int out_size, void* d_ws, size_t ws_size,
                              hipStream_t stream)
{
    const void* x   = d_in[0];
    const void* stf = d_in[1];
    const void* Mi  = d_in[2];
    const void* Mf  = d_in[3];
    const void* Wq  = d_in[4];  const void* bq = d_in[5];
    const void* Wk  = d_in[6];  const void* bk = d_in[7];
    const void* Wv  = d_in[8];  const void* bv = d_in[9];
    const void* Wg  = d_in[10]; const void* bg = d_in[11];
    const void* Wo  = d_in[12]; const void* bo = d_in[13];
    const void* lnw = d_in[14]; const void* lnb = d_in[15];

    int*   flag  = (int*)d_ws;
    float* base  = (float*)d_ws + 64;
    float*  f_u   = base;                        // u_proj fp32 (4 MB)
    float*  f_phi = base + 1048576;              // phi fp32 (2 MB)
    float*  f_w   = base + 1572864;              // conv accum -> x_tilde (4 MB, zeroed)
    float*  f_Y   = base + 2621440;              // attn accum fp32 (4 MB, zeroed)
    __bf16* f_Q   = (__bf16*)(base + 3670016);   // bf16 2048x512 each (2 MB)
    __bf16* f_K   = f_Q + 1048576;
    __bf16* f_V   = f_K + 1048576;
    __bf16* f_G   = f_V + 1048576;
    // total ws: 256 B + 22 MB

    dim3 blk(256);

    detect_k<<<1, blk, 0, stream>>>(x, flag);
    zero_k<<<2048, blk, 0, stream>>>((float4*)f_w, 524288);   // f_w + f_Y (contiguous 8 MB)

    mega_gemm<<<dim3(8, 32, 6), blk, 0, stream>>>(
        x, Mi, stf, Mf, Wq, bq, Wk, bk, Wv, bv, Wg, bg,
        f_u, f_phi, f_Q, f_K, f_V, f_G, flag);

    conv_attn_k<<<dim3(136, 8, 4), blk, 0, stream>>>(f_u, f_phi, f_w, f_Q, f_K, f_V, f_Y);

    ln_k<<<dim3(T_SEQ, BATCH), blk, 0, stream>>>(f_w, lnw, lnb, flag);

    final_gemm<<<dim3(8, 32), blk, 0, stream>>>(f_G, f_Y, f_w, Wo, bo, d_out, flag);
}

// Round 7
// 193.264 us; speedup vs baseline: 3.7922x; 1.0938x over previous
//
#include <hip/hip_runtime.h>
#include <hip/hip_bf16.h>

#define T_SEQ 1024
#define D_MOD 512
#define NHEAD 8
#define HDIM  64
#define R_DIM 512
#define BATCH 2

typedef __attribute__((ext_vector_type(8))) __bf16 bf16x8;
typedef __attribute__((ext_vector_type(4))) float f32x4;

// runtime-dtype load/store: bf==1 -> bf16, bf==0 -> fp32 (wave-uniform branch)
__device__ __forceinline__ float ldin(const void* p, size_t i, int bf) {
    if (bf) return __bfloat162float(((const __hip_bfloat16*)p)[i]);
    return ((const float*)p)[i];
}
__device__ __forceinline__ void stout(void* p, size_t i, int bf, float v) {
    if (bf) ((__hip_bfloat16*)p)[i] = __float2bfloat16(v);
    else    ((float*)p)[i] = v;
}

__device__ __forceinline__ float gelu_f(float x) {
    return 0.5f * x * (1.f + tanhf(0.7978845608028654f * (x + 0.044715f * x * x * x)));
}

// Inline dtype sniff (replaces the detect_k dispatch): fp32 N(0,1) data has
// ~0.4% of 16-bit halves matching bf16 inf/nan exponent; bf16 data has none.
// Returns 1 for bf16. Uniform across the block; ~32 coalesced loads/thread.
__device__ __forceinline__ int detect_bf(const void* x) {
    __shared__ int cnt;
    if (threadIdx.x == 0) cnt = 0;
    __syncthreads();
    const unsigned short* h = (const unsigned short*)x;
    int c = 0;
    for (int i = threadIdx.x; i < 8192; i += 256)
        if ((h[i] & 0x7F80u) == 0x7F80u) c++;
    if (c) atomicAdd(&cnt, c);
    __syncthreads();
    return cnt == 0;
}

// ---------------- fused projection GEMMs + zero job, one dispatch ----------------
// job 0: u   = x @ Mi                  -> fp32 fu
// job 1: Q   = gelu(x @ Wq^T + bq)     -> bf16 fQ   [b][t][h*64+p]
// job 2: K   = gelu(x @ Wk^T + bk)     -> bf16 fKT  [b][h][p][t]  (pre-transposed)
// job 3: V   = gelu(x @ Wv^T + bv)     -> bf16 fV
// job 4: G   = sigmoid(x @ Wg^T + bg)  -> bf16 fG
// job 5: phi = stf @ Mf                -> fp32 fphi (M=1024, K=24 pad 32)
// job 6: zero the 8 MB accumulation region (fw, fY contiguous)
__global__ __launch_bounds__(256) void mega_gemm(
    const void* __restrict__ x, const void* __restrict__ Mi,
    const void* __restrict__ stf, const void* __restrict__ Mf,
    const void* __restrict__ Wq, const void* __restrict__ bq,
    const void* __restrict__ Wk, const void* __restrict__ bk,
    const void* __restrict__ Wv, const void* __restrict__ bv,
    const void* __restrict__ Wg, const void* __restrict__ bg,
    float* __restrict__ fu, float* __restrict__ fphi,
    __bf16* __restrict__ fQ, __bf16* __restrict__ fKT,
    __bf16* __restrict__ fV, __bf16* __restrict__ fG)
{
    const int tid = threadIdx.x;
    const int job = blockIdx.z;
    if (job == 6) {
        float4* zp = (float4*)fu;               // fw..fY region passed via fu? no:
        // zero region starts at fw == fphi + 524288; compute from fphi to avoid
        // extra params: fw = fphi + 524288, length 2M float4 (8 MB)
        zp = (float4*)(fphi + 524288);
        const int bid = blockIdx.y * 8 + blockIdx.x;    // 0..255
        const float4 z4 = make_float4(0.f, 0.f, 0.f, 0.f);
        #pragma unroll
        for (int q = 0; q < 8; ++q)
            zp[bid * 2048 + q * 256 + tid] = z4;
        return;
    }
    const int bf = detect_bf(x);
    const void* A = x; const void* Bw; const void* bias = nullptr;
    int Kd = 512, act = 0; bool trb = true;
    switch (job) {
        case 0: Bw = Mi; trb = false; break;
        case 1: Bw = Wq; bias = bq; act = 1; break;
        case 2: Bw = Wk; bias = bk; act = 1; break;
        case 3: Bw = Wv; bias = bv; act = 1; break;
        case 4: Bw = Wg; bias = bg; act = 2; break;
        default: A = stf; Bw = Mf; trb = false; Kd = 32; break;
    }
    const int M = (job == 5) ? 1024 : 2048;
    const int m0 = blockIdx.y * 64;
    if (m0 >= M) return;
    const int n0 = blockIdx.x * 64;

    __shared__ __align__(16) __bf16 As[64][40];
    __shared__ __align__(16) __bf16 Bs[64][40];
    const int wave = tid >> 6, lane = tid & 63;
    const int lm = lane & 15, kq = lane >> 4;

    f32x4 acc[4] = {{0.f,0.f,0.f,0.f},{0.f,0.f,0.f,0.f},
                    {0.f,0.f,0.f,0.f},{0.f,0.f,0.f,0.f}};

    for (int k0 = 0; k0 < Kd; k0 += 32) {
        if (k0) __syncthreads();
        {
            const int mo = tid >> 2;
            const int ko = (tid & 3) * 8;
            if (job == 5) {
                #pragma unroll
                for (int q = 0; q < 8; ++q) {
                    const int k = ko + q;
                    As[mo][k] = (k < 24) ? (__bf16)ldin(A, (size_t)(m0 + mo) * 24 + k, bf)
                                         : (__bf16)0.f;
                }
            } else {
                const size_t off = (size_t)(m0 + mo) * 512 + k0 + ko;
                if (bf) {
                    *(bf16x8*)&As[mo][ko] = *(const bf16x8*)((const __bf16*)A + off);
                } else {
                    const float* Af = (const float*)A + off;
                    const float4 f0 = *(const float4*)Af;
                    const float4 f1 = *(const float4*)(Af + 4);
                    bf16x8 t;
                    t[0]=(__bf16)f0.x; t[1]=(__bf16)f0.y; t[2]=(__bf16)f0.z; t[3]=(__bf16)f0.w;
                    t[4]=(__bf16)f1.x; t[5]=(__bf16)f1.y; t[6]=(__bf16)f1.z; t[7]=(__bf16)f1.w;
                    *(bf16x8*)&As[mo][ko] = t;
                }
            }
        }
        if (trb) {
            const int no = tid >> 2;
            const int ko = (tid & 3) * 8;
            const size_t off = (size_t)(n0 + no) * 512 + k0 + ko;
            if (bf) {
                *(bf16x8*)&Bs[no][ko] = *(const bf16x8*)((const __bf16*)Bw + off);
            } else {
                const float* Bf = (const float*)Bw + off;
                const float4 f0 = *(const float4*)Bf;
                const float4 f1 = *(const float4*)(Bf + 4);
                bf16x8 t;
                t[0]=(__bf16)f0.x; t[1]=(__bf16)f0.y; t[2]=(__bf16)f0.z; t[3]=(__bf16)f0.w;
                t[4]=(__bf16)f1.x; t[5]=(__bf16)f1.y; t[6]=(__bf16)f1.z; t[7]=(__bf16)f1.w;
                *(bf16x8*)&Bs[no][ko] = t;
            }
        } else {
            const int kk = tid >> 3;
            const int nn = (tid & 7) * 8;
            if (job == 5) {
                #pragma unroll
                for (int q = 0; q < 8; ++q)
                    Bs[nn + q][kk] = (kk < 24) ? (__bf16)ldin(Bw, (size_t)kk * 512 + n0 + nn + q, bf)
                                               : (__bf16)0.f;
            } else {
                const size_t off = (size_t)(k0 + kk) * 512 + n0 + nn;
                if (bf) {
                    const bf16x8 t = *(const bf16x8*)((const __bf16*)Bw + off);
                    #pragma unroll
                    for (int q = 0; q < 8; ++q) Bs[nn + q][kk] = t[q];
                } else {
                    const float* Bf = (const float*)Bw + off;
                    #pragma unroll
                    for (int q = 0; q < 8; ++q) Bs[nn + q][kk] = (__bf16)Bf[q];
                }
            }
        }
        __syncthreads();
        const bf16x8 a = *(const bf16x8*)&As[wave * 16 + lm][kq * 8];
        #pragma unroll
        for (int nt = 0; nt < 4; ++nt) {
            const bf16x8 b = *(const bf16x8*)&Bs[nt * 16 + lm][kq * 8];
            acc[nt] = __builtin_amdgcn_mfma_f32_16x16x32_bf16(a, b, acc[nt], 0, 0, 0);
        }
    }
    // epilogue: D[m][n]: m = wave*16 + kq*4 + r2, n = nt*16 + lm
    #pragma unroll
    for (int nt = 0; nt < 4; ++nt) {
        const int n = n0 + nt * 16 + lm;
        #pragma unroll
        for (int r2 = 0; r2 < 4; ++r2) {
            const int m = m0 + wave * 16 + kq * 4 + r2;
            float v = acc[nt][r2];
            if (bias) v += ldin(bias, (size_t)n, bf);
            if (act == 1) v = gelu_f(v);
            if (act == 2) v = 1.f / (1.f + expf(-v));
            switch (job) {
                case 0: fu[(size_t)m * 512 + n] = v; break;
                case 5: fphi[(size_t)m * 512 + n] = v; break;
                case 1: fQ[(size_t)m * 512 + n] = (__bf16)v; break;
                case 3: fV[(size_t)m * 512 + n] = (__bf16)v; break;
                case 4: fG[(size_t)m * 512 + n] = (__bf16)v; break;
                case 2: {  // K transposed: [b][h][p][t]
                    const int b = m >> 10, t = m & 1023;
                    const int h = n >> 6,  p = n & 63;
                    fKT[(((size_t)b * NHEAD + h) * 64 + p) * T_SEQ + t] = (__bf16)v;
                    break;
                }
            }
        }
    }
}

// ---------------- fused uniform-task conv + attention, 4 j-tiles per block ----
// blockIdx.x = flat (ti, jc) task in [0,40): jc covers j in [4jc, min(4jc+3,ti)].
// z<2: conv (b=z, y=r-tile); z>=2: attn (b=z-2, y=head).
// Register accumulation across the chunk; ONE atomic flush per block.
__global__ __launch_bounds__(256) void conv_attn_k(
    const float* __restrict__ u, const float* __restrict__ vphi,
    float* __restrict__ w,
    const __bf16* __restrict__ Q, const __bf16* __restrict__ KT,
    const __bf16* __restrict__ V, float* __restrict__ Y)
{
    __shared__ __align__(16) unsigned char smem[49152];
    const int tid = threadIdx.x;
    const int z = blockIdx.z;
    // decode flat task -> (ti, jlo..jhi); counts per ti = (ti+4)>>2, total 40
    int rem = blockIdx.x, ti = 0;
    while (rem >= ((ti + 4) >> 2)) { rem -= (ti + 4) >> 2; ++ti; }
    const int jlo = rem * 4;
    const int jhi = (jlo + 3 < ti) ? jlo + 3 : ti;
    const int t0 = ti * 64;

    if (z < 2) {
        // ---- conv: w[b, t0:t0+64, r0:r0+64] += sum of lag tiles jlo..jhi
        float (*vs)[64] = (float (*)[64])smem;            // 16 KB
        float (*us)[64] = (float (*)[64])(smem + 16384);  // 32 KB
        const int rl = tid & 63, tg = tid >> 6;
        const int b = z;
        const int r0 = blockIdx.y * 64;
        const float* ub = u + (size_t)b * T_SEQ * R_DIM;
        float acc[16] = {};
        for (int j = jlo; j <= jhi; ++j) {
            if (j != jlo) __syncthreads();
            const int L0 = j * 64;
            const int W0 = t0 - L0 - 63;
            #pragma unroll
            for (int jj = 0; jj < 8; ++jj) {
                const int n = jj * 256 + tid;
                const int row = n >> 4, c4 = (n & 15) * 4;
                int s = W0 + row;
                s = s < 0 ? 0 : (s > T_SEQ - 1 ? T_SEQ - 1 : s);
                *(float4*)&us[row][c4] = *(const float4*)&ub[(size_t)s * R_DIM + r0 + c4];
            }
            #pragma unroll
            for (int jj = 0; jj < 4; ++jj) {
                const int n = jj * 256 + tid;
                const int row = n >> 4, c4 = (n & 15) * 4;
                *(float4*)&vs[row][c4] = *(const float4*)&vphi[(size_t)(L0 + row) * R_DIM + r0 + c4];
            }
            __syncthreads();
            if (j < ti) {
                #pragma unroll
                for (int g = 0; g < 4; ++g) {
                    const int wsmin = tg * 16 + 49 - 16 * g;
                    float ur[30];
                    #pragma unroll
                    for (int q = 0; q < 30; ++q) ur[q] = us[wsmin + q][rl];
                    float vr[8];
                    #pragma unroll
                    for (int e = 0; e < 8; ++e) vr[e] = vs[16 * g + 2 * e][rl];
                    #pragma unroll
                    for (int e = 0; e < 8; ++e)
                        #pragma unroll
                        for (int i = 0; i < 16; ++i)
                            acc[i] += vr[e] * ur[i - 2 * e + 14];
                }
            } else {
                for (int l = 0; l < 64; l += 2) {
                    const float vv = vs[l][rl];
                    #pragma unroll
                    for (int i = 0; i < 16; ++i) {
                        const int srel = tg * 16 + i - l;
                        if (srel >= 0) acc[i] += vv * us[srel + 63][rl];
                    }
                }
            }
        }
        #pragma unroll
        for (int i = 0; i < 16; ++i)
            atomicAdd(&w[((size_t)b * T_SEQ + t0 + tg * 16 + i) * R_DIM + r0 + rl],
                      2.f * acc[i]);
    } else {
        // ---- attn: Y[b,h,t-tile ti] += sum over s-tiles jlo..jhi of tril(QV^T)K
        __bf16 (*Qs)[72] = (__bf16 (*)[72])smem;              // 9216 B each
        __bf16 (*Vs)[72] = (__bf16 (*)[72])(smem + 9216);
        __bf16 (*Kt)[72] = (__bf16 (*)[72])(smem + 18432);
        __bf16 (*Sa)[72] = (__bf16 (*)[72])(smem + 27648);
        const int wave = tid >> 6, lane = tid & 63;
        const int lm = lane & 15, kq = lane >> 4;
        const int b = z - 2;
        const int h = blockIdx.y;
        const size_t cbase = ((size_t)b * T_SEQ) * D_MOD + h * HDIM;
        const __bf16* KTh = KT + (((size_t)b * NHEAD + h) * 64) * T_SEQ;
        #pragma unroll
        for (int it = 0; it < 2; ++it) {
            const int n = it * 256 + tid;
            const int row = n >> 3, p0 = (n & 7) * 8;
            *(bf16x8*)&Qs[row][p0] = *(const bf16x8*)&Q[cbase + (size_t)(t0 + row) * D_MOD + p0];
        }
        f32x4 accY[4] = {{0.f,0.f,0.f,0.f},{0.f,0.f,0.f,0.f},
                         {0.f,0.f,0.f,0.f},{0.f,0.f,0.f,0.f}};
        for (int j = jlo; j <= jhi; ++j) {
            const int s0 = j * 64;
            __syncthreads();
            #pragma unroll
            for (int it = 0; it < 2; ++it) {
                const int n = it * 256 + tid;
                const int row = n >> 3, c0 = (n & 7) * 8;
                *(bf16x8*)&Vs[row][c0] = *(const bf16x8*)&V[cbase + (size_t)(s0 + row) * D_MOD + c0];
                // K pre-transposed: row-major coalesced stage, no scatter
                *(bf16x8*)&Kt[row][c0] = *(const bf16x8*)&KTh[(size_t)row * T_SEQ + s0 + c0];
            }
            __syncthreads();
            f32x4 sacc[4] = {{0.f,0.f,0.f,0.f},{0.f,0.f,0.f,0.f},
                             {0.f,0.f,0.f,0.f},{0.f,0.f,0.f,0.f}};
            #pragma unroll
            for (int ks = 0; ks < 2; ++ks) {
                const bf16x8 a = *(const bf16x8*)&Qs[wave * 16 + lm][ks * 32 + kq * 8];
                #pragma unroll
                for (int nt = 0; nt < 4; ++nt) {
                    const bf16x8 bb = *(const bf16x8*)&Vs[nt * 16 + lm][ks * 32 + kq * 8];
                    sacc[nt] = __builtin_amdgcn_mfma_f32_16x16x32_bf16(a, bb, sacc[nt], 0, 0, 0);
                }
            }
            // mask + stash S bf16 in own wave's 16-row strip (no barrier: wave w
            // writes rows [16w,16w+16) and reads only those rows in matmul2)
            const bool diag = (j == ti);
            #pragma unroll
            for (int nt = 0; nt < 4; ++nt) {
                const int sl = nt * 16 + lm;
                #pragma unroll
                for (int r2 = 0; r2 < 4; ++r2) {
                    const int tl = wave * 16 + kq * 4 + r2;
                    float v = sacc[nt][r2];
                    if (diag && sl > tl) v = 0.f;
                    Sa[tl][sl] = (__bf16)v;
                }
            }
            #pragma unroll
            for (int ks = 0; ks < 2; ++ks) {
                const bf16x8 a = *(const bf16x8*)&Sa[wave * 16 + lm][ks * 32 + kq * 8];
                #pragma unroll
                for (int nt = 0; nt < 4; ++nt) {
                    const bf16x8 bb = *(const bf16x8*)&Kt[nt * 16 + lm][ks * 32 + kq * 8];
                    accY[nt] = __builtin_amdgcn_mfma_f32_16x16x32_bf16(a, bb, accY[nt], 0, 0, 0);
                }
            }
        }
        #pragma unroll
        for (int nt = 0; nt < 4; ++nt) {
            const int nh = nt * 16 + lm;
            #pragma unroll
            for (int r2 = 0; r2 < 4; ++r2) {
                const int tl = wave * 16 + kq * 4 + r2;
                atomicAdd(&Y[cbase + (size_t)(t0 + tl) * D_MOD + nh], accY[nt][r2]);
            }
        }
    }
}

// in-place layernorm over last dim (512), fp32 buffer
__global__ __launch_bounds__(256) void ln_k(float* __restrict__ w,
                                            const void* __restrict__ g,
                                            const void* __restrict__ b,
                                            const void* __restrict__ xref)
{
    const int bf = detect_bf(xref);
    const size_t row = (size_t)blockIdx.y * T_SEQ + blockIdx.x;
    float* p = w + row * R_DIM;
    const int tid = threadIdx.x;
    const float x0 = p[tid], x1 = p[tid + 256];
    __shared__ float red[4];
    float s = x0 + x1;
    #pragma unroll
    for (int off = 32; off > 0; off >>= 1) s += __shfl_down(s, off, 64);
    if ((tid & 63) == 0) red[tid >> 6] = s;
    __syncthreads();
    const float mu = (red[0] + red[1] + red[2] + red[3]) * (1.f / 512.f);
    __syncthreads();
    const float d0 = x0 - mu, d1 = x1 - mu;
    float vsum = d0 * d0 + d1 * d1;
    #pragma unroll
    for (int off = 32; off > 0; off >>= 1) vsum += __shfl_down(vsum, off, 64);
    if ((tid & 63) == 0) red[tid >> 6] = vsum;
    __syncthreads();
    const float var = (red[0] + red[1] + red[2] + red[3]) * (1.f / 512.f);
    const float rs = rsqrtf(var + 1e-5f);
    p[tid]       = d0 * rs * ldin(g, tid, bf)       + ldin(b, tid, bf);
    p[tid + 256] = d1 * rs * ldin(g, tid + 256, bf) + ldin(b, tid + 256, bf);
}

// ---------------- final GEMM with fused comb: out = (g*y+(1-g)*xt) @ Wo^T + bo
__global__ __launch_bounds__(256) void final_gemm(const __bf16* __restrict__ G,
                                                  const float* __restrict__ Yf,
                                                  const float* __restrict__ Xt,
                                                  const void* __restrict__ Wo,
                                                  const void* __restrict__ bo,
                                                  void* __restrict__ out,
                                                  const void* __restrict__ xref)
{
    const int bf = detect_bf(xref);
    __shared__ __align__(16) __bf16 As[64][40];
    __shared__ __align__(16) __bf16 Bs[64][40];
    const int tid = threadIdx.x;
    const int wave = tid >> 6, lane = tid & 63;
    const int lm = lane & 15, kq = lane >> 4;
    const int m0 = blockIdx.y * 64, n0 = blockIdx.x * 64;

    f32x4 acc[4] = {{0.f,0.f,0.f,0.f},{0.f,0.f,0.f,0.f},
                    {0.f,0.f,0.f,0.f},{0.f,0.f,0.f,0.f}};

    for (int k0 = 0; k0 < 512; k0 += 32) {
        __syncthreads();
        {
            const int mo = tid >> 2;
            const int ko = (tid & 3) * 8;
            const size_t off = (size_t)(m0 + mo) * 512 + k0 + ko;
            const bf16x8 g8 = *(const bf16x8*)(G + off);
            const float4 y0 = *(const float4*)(Yf + off);
            const float4 y1 = *(const float4*)(Yf + off + 4);
            const float4 x0 = *(const float4*)(Xt + off);
            const float4 x1 = *(const float4*)(Xt + off + 4);
            const float yv[8] = {y0.x,y0.y,y0.z,y0.w,y1.x,y1.y,y1.z,y1.w};
            const float xv[8] = {x0.x,x0.y,x0.z,x0.w,x1.x,x1.y,x1.z,x1.w};
            bf16x8 t;
            #pragma unroll
            for (int q = 0; q < 8; ++q) {
                const float gg = (float)g8[q];
                t[q] = (__bf16)(gg * yv[q] + (1.f - gg) * xv[q]);
            }
            *(bf16x8*)&As[mo][ko] = t;
        }
        {
            const int no = tid >> 2;
            const int ko = (tid & 3) * 8;
            const size_t off = (size_t)(n0 + no) * 512 + k0 + ko;
            if (bf) {
                *(bf16x8*)&Bs[no][ko] = *(const bf16x8*)((const __bf16*)Wo + off);
            } else {
                const float* Bf = (const float*)Wo + off;
                const float4 f0 = *(const float4*)Bf;
                const float4 f1 = *(const float4*)(Bf + 4);
                bf16x8 t;
                t[0]=(__bf16)f0.x; t[1]=(__bf16)f0.y; t[2]=(__bf16)f0.z; t[3]=(__bf16)f0.w;
                t[4]=(__bf16)f1.x; t[5]=(__bf16)f1.y; t[6]=(__bf16)f1.z; t[7]=(__bf16)f1.w;
                *(bf16x8*)&Bs[no][ko] = t;
            }
        }
        __syncthreads();
        const bf16x8 a = *(const bf16x8*)&As[wave * 16 + lm][kq * 8];
        #pragma unroll
        for (int nt = 0; nt < 4; ++nt) {
            const bf16x8 b = *(const bf16x8*)&Bs[nt * 16 + lm][kq * 8];
            acc[nt] = __builtin_amdgcn_mfma_f32_16x16x32_bf16(a, b, acc[nt], 0, 0, 0);
        }
    }
    #pragma unroll
    for (int nt = 0; nt < 4; ++nt) {
        const int n = n0 + nt * 16 + lm;
        #pragma unroll
        for (int r2 = 0; r2 < 4; ++r2) {
            const int m = m0 + wave * 16 + kq * 4 + r2;
            float v = acc[nt][r2] + ldin(bo, (size_t)n, bf);
            stout(out, (size_t)m * 512 + n, bf, v);
        }
    }
}

extern "C" void kernel_launch(void* const* d_in, const int* in_sizes, int n_in,
                              void* d_out, int out_size, void* d_ws, size_t ws_size,
                              hipStream_t stream)
{
    const void* x   = d_in[0];
    const void* stf = d_in[1];
    const void* Mi  = d_in[2];
    const void* Mf  = d_in[3];
    const void* Wq  = d_in[4];  const void* bq = d_in[5];
    const void* Wk  = d_in[6];  const void* bk = d_in[7];
    const void* Wv  = d_in[8];  const void* bv = d_in[9];
    const void* Wg  = d_in[10]; const void* bg = d_in[11];
    const void* Wo  = d_in[12]; const void* bo = d_in[13];
    const void* lnw = d_in[14]; const void* lnb = d_in[15];

    float* base = (float*)d_ws;
    float*  f_u   = base;                        // u_proj fp32 (4 MB)
    float*  f_phi = base + 1048576;              // phi fp32 (2 MB)
    float*  f_w   = base + 1572864;              // conv accum -> x_tilde (4 MB, zeroed)
    float*  f_Y   = base + 2621440;              // attn accum fp32 (4 MB, zeroed)
    __bf16* f_Q   = (__bf16*)(base + 3670016);   // bf16 2048x512 (2 MB)
    __bf16* f_KT  = f_Q + 1048576;               // bf16 K transposed [b][h][p][t]
    __bf16* f_V   = f_KT + 1048576;
    __bf16* f_G   = f_V + 1048576;
    // total ws: ~23 MB

    dim3 blk(256);

    // jobs 0-5 GEMMs, job 6 zeroes f_w+f_Y (8 MB contiguous from f_phi+524288)
    mega_gemm<<<dim3(8, 32, 7), blk, 0, stream>>>(
        x, Mi, stf, Mf, Wq, bq, Wk, bk, Wv, bv, Wg, bg,
        f_u, f_phi, f_Q, f_KT, f_V, f_G);

    conv_attn_k<<<dim3(40, 8, 4), blk, 0, stream>>>(f_u, f_phi, f_w, f_Q, f_KT, f_V, f_Y);

    ln_k<<<dim3(T_SEQ, BATCH), blk, 0, stream>>>(f_w, lnw, lnb, x);

    final_gemm<<<dim3(8, 32), blk, 0, stream>>>(f_G, f_Y, f_w, Wo, bo, d_out, x);
}